// Round 8
// baseline (385.651 us; speedup 1.0000x reference)
//
#include <hip/hip_runtime.h>
#include <hip/hip_bf16.h>

#define N_NODES 100000
#define N_EDGES 1600000
#define F_IN 128
#define HID 64
#define SCAN_NB 98   // ceil(100000/1024) — grid for detect
#define NBUCK 782    // ceil(100000/128) column buckets
#define BSH 7        // 128 nodes per bucket
#define NSCB 392     // blocks for count/scatter passes

typedef __attribute__((ext_vector_type(8))) short short8;
typedef __attribute__((ext_vector_type(2))) float vf2;

__device__ __forceinline__ float bfbits2f(unsigned short u) {
    union { unsigned int i; float f; } v;
    v.i = ((unsigned int)u) << 16;
    return v.f;
}
__device__ __forceinline__ unsigned short f2bfbits(float f) {
    union { float f; unsigned int i; } v;
    v.f = f;
    unsigned int r = v.i + 0x7FFFu + ((v.i >> 16) & 1u);  // RNE
    return (unsigned short)(r >> 16);
}
__device__ __forceinline__ unsigned int pack2bf(float a, float b) {
    return ((unsigned int)f2bfbits(b) << 16) | (unsigned int)f2bfbits(a);
}
__device__ __forceinline__ float lo_bf(unsigned int w) { return bfbits2f((unsigned short)(w & 0xFFFF)); }
__device__ __forceinline__ float hi_bf(unsigned int w) { return bfbits2f((unsigned short)(w >> 16)); }
// unpack u32 (2 packed bf16) -> float2: {lo<<16, hi&mask} reinterpreted. 2 VALU ops for 2 channels.
__device__ __forceinline__ vf2 unpack_bf2(unsigned int w) {
    union { unsigned int i[2]; vf2 f; } u;
    u.i[0] = w << 16;
    u.i[1] = w & 0xFFFF0000u;
    return u.f;
}

// ---- detect flags AND zero bucket counters; block 0 does flag logic ----
__global__ void k_detect(const int* __restrict__ ei, const unsigned int* __restrict__ x32,
                         int* __restrict__ flag, int* __restrict__ gcount) {
    int gid = blockIdx.x * 1024 + threadIdx.x;
    if (gid < NBUCK) gcount[gid] = 0;
    if (blockIdx.x != 0) return;
    __shared__ int s_odd, s_cnt;
    if (threadIdx.x == 0) { s_odd = 0; s_cnt = 0; }
    __syncthreads();
    int t = threadIdx.x;  // 1024 threads
    if (ei[2 * t + 1] != 0) atomicOr(&s_odd, 1);
    if (t < 256) {
        unsigned int u = x32[t];
        unsigned int e = (u >> 7) & 0xFF;
        if (e >= 0x68 && e <= 0x97) atomicAdd(&s_cnt, 1);
    }
    __syncthreads();
    if (t == 0) {
        flag[0] = (s_odd == 0) ? 1 : 0;
        flag[1] = (s_cnt >= 160) ? 1 : 0;
    }
}

__device__ __forceinline__ int clampN(int v) {
    v = v < 0 ? 0 : v;
    return v > (N_NODES - 1) ? (N_NODES - 1) : v;
}
__device__ __forceinline__ int load_row(const int* __restrict__ ei, int f, int e) {
    return clampN(f ? ei[2 * e] : ei[e]);
}
__device__ __forceinline__ int load_col(const int* __restrict__ ei, int f, int e) {
    return clampN(f ? ei[2 * (N_EDGES + e)] : ei[N_EDGES + e]);
}

// ---- fp32 weight scratch layout (floats) ----
#define WF_W1   0
#define WF_W2   8192
#define WF_L1W  12288
#define WF_B1   20480
#define WF_B2   20544
#define WF_L1B  20608
#define WF_L2W  20672
#define WF_L2B  20800
#define WF_TOT  20802

__global__ void k_prep(const void* W1, const void* W2, const void* L1W,
                       const void* b1, const void* b2, const void* L1b,
                       const void* L2W, const void* L2b,
                       const int* __restrict__ flag, float* __restrict__ Wf) {
    int idx = blockIdx.x * blockDim.x + threadIdx.x;
    if (idx >= WF_TOT) return;
    int bf = flag[1];
    const void* src; int k;
    if      (idx < WF_W2)  { src = W1;  k = idx; }
    else if (idx < WF_L1W) { src = W2;  k = idx - WF_W2; }
    else if (idx < WF_B1)  { src = L1W; k = idx - WF_L1W; }
    else if (idx < WF_B2)  { src = b1;  k = idx - WF_B1; }
    else if (idx < WF_L1B) { src = b2;  k = idx - WF_B2; }
    else if (idx < WF_L2W) { src = L1b; k = idx - WF_L1B; }
    else if (idx < WF_L2B) { src = L2W; k = idx - WF_L2W; }
    else                   { src = L2b; k = idx - WF_L2B; }
    Wf[idx] = bf ? bfbits2f(((const unsigned short*)src)[k]) : ((const float*)src)[k];
}

// ===== bucketed CSR build (deterministic, no global cursor atomics) =====

// ---- pass 1: LDS histogram; emit per-block hist matrix + global bucket counts ----
__global__ void __launch_bounds__(256) k_bcount(const int* __restrict__ ei,
                                                const int* __restrict__ flag,
                                                int* __restrict__ gcount,
                                                int* __restrict__ bhist) {
    __shared__ int hist[NBUCK];
    for (int t = threadIdx.x; t < NBUCK; t += 256) hist[t] = 0;
    __syncthreads();
    int f = flag[0];
    const int EPB = (N_EDGES + NSCB - 1) / NSCB;
    int base = blockIdx.x * EPB;
    int end = base + EPB; if (end > N_EDGES) end = N_EDGES;
    for (int e = base + threadIdx.x; e < end; e += 256)
        atomicAdd(&hist[load_col(ei, f, e) >> BSH], 1);
    __syncthreads();
    for (int t = threadIdx.x; t < NBUCK; t += 256) {
        int hv = hist[t];
        bhist[(size_t)blockIdx.x * NBUCK + t] = hv;   // coalesced
        if (hv) atomicAdd(&gcount[t], hv);
    }
}

// ---- pass 2a: exclusive scan of 782 bucket totals -> bbase ----
__global__ void k_bscan(const int* __restrict__ gcount,
                        int* __restrict__ bbase, int* __restrict__ rowptr) {
    __shared__ int s[1024];
    int t = threadIdx.x;
    int v = (t < NBUCK) ? gcount[t] : 0;
    s[t] = v; __syncthreads();
    for (int off = 1; off < 1024; off <<= 1) {
        int add = (t >= off) ? s[t - off] : 0;
        __syncthreads();
        s[t] += add;
        __syncthreads();
    }
    if (t < NBUCK) bbase[t] = s[t] - v;
    if (t == 0) { bbase[NBUCK] = N_EDGES; rowptr[N_NODES] = N_EDGES; }
}

// ---- pass 2b: per-(block,bucket) exact bases: bofs[b][blk] = bbase[b] + prefix ----
__global__ void __launch_bounds__(512) k_bscan2(const int* __restrict__ bhist,
                                                const int* __restrict__ bbase,
                                                int* __restrict__ bofs) {
    __shared__ int s[512];
    int b = blockIdx.x;
    int t = threadIdx.x;
    int v = (t < NSCB) ? bhist[(size_t)t * NBUCK + b] : 0;
    s[t] = v; __syncthreads();
    for (int off = 1; off < 512; off <<= 1) {
        int add = (t >= off) ? s[t - off] : 0;
        __syncthreads();
        s[t] += add;
        __syncthreads();
    }
    if (t < NSCB) bofs[(size_t)b * NSCB + t] = bbase[b] + s[t] - v;  // coalesced
}

// ---- pass 3: single-read scatter; rank via LDS atomics only ----
__global__ void __launch_bounds__(256) k_bscatter(const int* __restrict__ ei,
                                                  const int* __restrict__ flag,
                                                  const int* __restrict__ bofs,
                                                  unsigned int* __restrict__ tmp) {
    __shared__ int lbase[NBUCK];
    __shared__ int rank[NBUCK];
    for (int t = threadIdx.x; t < NBUCK; t += 256) {
        lbase[t] = bofs[(size_t)t * NSCB + blockIdx.x];
        rank[t] = 0;
    }
    __syncthreads();
    int f = flag[0];
    const int EPB = (N_EDGES + NSCB - 1) / NSCB;
    int base = blockIdx.x * EPB;
    int end = base + EPB; if (end > N_EDGES) end = N_EDGES;
    for (int e = base + threadIdx.x; e < end; e += 256) {
        int r = load_row(ei, f, e), c = load_col(ei, f, e);
        int b = c >> BSH;
        int rk = atomicAdd(&rank[b], 1);
        tmp[lbase[b] + rk] = ((unsigned int)r << BSH) | (unsigned int)(c & 127);
    }
}

// ---- pass 4: per-bucket sub-CSR entirely in LDS (emits csr_src, rowptr, dinv) ----
__global__ void __launch_bounds__(256) k_bcsr(const unsigned int* __restrict__ tmp,
                                              const int* __restrict__ bbase,
                                              int* __restrict__ rowptr,
                                              float* __restrict__ dinv,
                                              int* __restrict__ csr_src) {
    __shared__ int nh[128];    // per-node counts (stable after count phase)
    __shared__ int nrp[128];   // inclusive prefix
    __shared__ int ncur[128];  // placement cursor
    int nb = blockIdx.x;
    int s0 = bbase[nb], s1 = bbase[nb + 1];
    int cnt = s1 - s0;
    int t = threadIdx.x;
    if (t < 128) { nh[t] = 0; ncur[t] = 0; }
    __syncthreads();
    for (int i = t; i < cnt; i += 256)
        atomicAdd(&nh[tmp[s0 + i] & 127], 1);
    __syncthreads();
    if (t < 128) nrp[t] = nh[t];
    __syncthreads();
    for (int off = 1; off < 128; off <<= 1) {
        int add = (t < 128 && t >= off) ? nrp[t - off] : 0;
        __syncthreads();
        if (t < 128) nrp[t] += add;
        __syncthreads();
    }
    int nodeBase = nb * 128;
    if (t < 128 && nodeBase + t < N_NODES) {
        rowptr[nodeBase + t] = s0 + nrp[t] - nh[t];  // exclusive prefix
        dinv[nodeBase + t] = rsqrtf((float)(nh[t] + 1));
    }
    __syncthreads();
    for (int i = t; i < cnt; i += 256) {
        unsigned int v = tmp[s0 + i];
        int cl = v & 127;
        int rk = atomicAdd(&ncur[cl], 1);
        csr_src[s0 + (nrp[cl] - nh[cl]) + rk] = (int)(v >> BSH);
    }
}

// ===== node tables: packed bf16 rows, 32 u32 (=64 ch) per node =====
__device__ __forceinline__ void fma8_32(const float* xv, const float* __restrict__ W,
                                        int k0, int coloff, float* acc) {
#pragma unroll
    for (int t = 0; t < 8; t++) {
        const float* wr = W + (k0 + t) * 64 + coloff;
#pragma unroll
        for (int j = 0; j < 32; j++) acc[j] = fmaf(xv[t], wr[j], acc[j]);
    }
}

// ---- layer-1 GEMM (wave-split): x [N,128] @ Wf[128,64] -> hs bf16; scale=dinv ----
__global__ void __launch_bounds__(256) k_gemm_in_ws(const void* __restrict__ x,
                                                    const float* __restrict__ Wf,
                                                    const float* __restrict__ dinv,
                                                    unsigned int* __restrict__ hs,
                                                    const int* __restrict__ flag) {
    int wv = __builtin_amdgcn_readfirstlane(threadIdx.x >> 6);  // 0..3, scalar
    int wid = blockIdx.x * 4 + wv;
    int group = wid >> 1;
    int half = wid & 1;          // scalar: col-half
    int lane = threadIdx.x & 63;
    int node = group * 64 + lane;
    if (node >= N_NODES) return;
    int bf = flag[1];
    int coloff = half * 32;
    float acc[32];
#pragma unroll
    for (int j = 0; j < 32; j++) acc[j] = 0.f;
    if (bf) {
        const unsigned short* xp = (const unsigned short*)x + (size_t)node * F_IN;
#pragma unroll 2
        for (int k0 = 0; k0 < F_IN; k0 += 8) {
            short8 raw = *(const short8*)(xp + k0);
            float xv[8];
#pragma unroll
            for (int t = 0; t < 8; t++) xv[t] = bfbits2f((unsigned short)raw[t]);
            fma8_32(xv, Wf, k0, coloff, acc);
        }
    } else {
        const float* xp = (const float*)x + (size_t)node * F_IN;
#pragma unroll 2
        for (int k0 = 0; k0 < F_IN; k0 += 8) {
            float4 a = *(const float4*)(xp + k0);
            float4 b = *(const float4*)(xp + k0 + 4);
            float xv[8] = {a.x, a.y, a.z, a.w, b.x, b.y, b.z, b.w};
            fma8_32(xv, Wf, k0, coloff, acc);
        }
    }
    float s = dinv[node];
    unsigned int* op = hs + (size_t)node * 32 + half * 16;
#pragma unroll
    for (int j = 0; j < 32; j += 2) op[j >> 1] = pack2bf(acc[j] * s, acc[j + 1] * s);
}

// ---- layer-2 GEMM (wave-split): in bf16 [N,64] @ W[64][64] -> out bf16; scale=dinv ----
__global__ void __launch_bounds__(256) k_gemm64_ws(const unsigned int* __restrict__ in,
                                                   const float* __restrict__ W,
                                                   const float* __restrict__ dinv,
                                                   unsigned int* __restrict__ out) {
    int wv = __builtin_amdgcn_readfirstlane(threadIdx.x >> 6);
    int wid = blockIdx.x * 4 + wv;
    int group = wid >> 1;
    int half = wid & 1;
    int lane = threadIdx.x & 63;
    int node = group * 64 + lane;
    if (node >= N_NODES) return;
    int coloff = half * 32;
    float acc[32];
#pragma unroll
    for (int j = 0; j < 32; j++) acc[j] = 0.f;
    const unsigned short* hp = (const unsigned short*)(in + (size_t)node * 32);
#pragma unroll 2
    for (int k0 = 0; k0 < 64; k0 += 8) {
        short8 raw = *(const short8*)(hp + k0);
        float xv[8];
#pragma unroll
        for (int t = 0; t < 8; t++) xv[t] = bfbits2f((unsigned short)raw[t]);
        fma8_32(xv, W, k0, coloff, acc);
    }
    float s = dinv[node];
    unsigned int* op = out + (size_t)node * 32 + half * 16;
#pragma unroll
    for (int j = 0; j < 32; j += 2) op[j >> 1] = pack2bf(acc[j] * s, acc[j + 1] * s);
}

// ---- edge-MLP projections (wave-split, 4 tasks): block = 64 nodes x 4 waves ----
__global__ void __launch_bounds__(256) k_pair_ws(unsigned int* __restrict__ h,
                                                 const float* __restrict__ W,  // L1W [128][64]
                                                 unsigned int* __restrict__ P1) {
    int task = __builtin_amdgcn_readfirstlane(threadIdx.x >> 6);  // 0..3, scalar
    int lane = threadIdx.x & 63;
    int node = blockIdx.x * 64 + lane;
    bool valid = node < N_NODES;
    int coloff = (task & 1) * 32;
    const float* Wb = W + (task >> 1) * 64 * 64;  // k-row base: P1 rows 0.., P2 rows 64..
    float acc[32];
#pragma unroll
    for (int j = 0; j < 32; j++) acc[j] = 0.f;
    if (valid) {
        const unsigned short* hp = (const unsigned short*)(h + (size_t)node * 32);
#pragma unroll 2
        for (int k0 = 0; k0 < 64; k0 += 8) {
            short8 raw = *(const short8*)(hp + k0);
            float xv[8];
#pragma unroll
            for (int t = 0; t < 8; t++) xv[t] = bfbits2f((unsigned short)raw[t]);
            fma8_32(xv, Wb, k0, coloff, acc);
        }
    }
    __syncthreads();  // all reads of this block's 64 h-rows complete before P2 writes
    if (valid) {
        unsigned int* op = (task < 2 ? P1 : h) + (size_t)node * 32 + coloff / 2;
#pragma unroll
        for (int j = 0; j < 32; j += 2) op[j >> 1] = pack2bf(acc[j], acc[j + 1]);
    }
}

// ---- fused aggregate: wave = 2 nodes; 32 lanes/node; x16 unroll for gather ILP
// (32 random lines in flight per wave) + packed-f32 accumulate ----
__global__ void __launch_bounds__(256) k_agg(const unsigned int* __restrict__ hs,
                                             const int* __restrict__ rowptr,
                                             const int* __restrict__ csr_src,
                                             const float* __restrict__ dinv,
                                             const float* __restrict__ bias,
                                             unsigned int* __restrict__ h) {
    int waves_per_blk = blockDim.x >> 6;
    int wid = blockIdx.x * waves_per_blk + (threadIdx.x >> 6);
    int lane = threadIdx.x & 63;
    int half = lane >> 5;
    int w = lane & 31;
    int node = wid * 2 + half;
    if (node >= N_NODES) return;
    vf2 a2 = unpack_bf2(hs[(size_t)node * 32 + w]);
    int k = rowptr[node], k1 = rowptr[node + 1];
    for (; k + 15 < k1; k += 16) {
        int sidx[16];
        unsigned int wv[16];
#pragma unroll
        for (int t = 0; t < 16; t++) sidx[t] = csr_src[k + t];
#pragma unroll
        for (int t = 0; t < 16; t++) wv[t] = hs[(size_t)sidx[t] * 32 + w];
        vf2 p0 = (unpack_bf2(wv[0]) + unpack_bf2(wv[1])) + (unpack_bf2(wv[2]) + unpack_bf2(wv[3]));
        vf2 p1 = (unpack_bf2(wv[4]) + unpack_bf2(wv[5])) + (unpack_bf2(wv[6]) + unpack_bf2(wv[7]));
        vf2 p2 = (unpack_bf2(wv[8]) + unpack_bf2(wv[9])) + (unpack_bf2(wv[10]) + unpack_bf2(wv[11]));
        vf2 p3 = (unpack_bf2(wv[12]) + unpack_bf2(wv[13])) + (unpack_bf2(wv[14]) + unpack_bf2(wv[15]));
        a2 += (p0 + p1) + (p2 + p3);
    }
    for (; k + 3 < k1; k += 4) {
        int s0 = csr_src[k], s1 = csr_src[k + 1], s2 = csr_src[k + 2], s3 = csr_src[k + 3];
        unsigned int w0 = hs[(size_t)s0 * 32 + w];
        unsigned int w1 = hs[(size_t)s1 * 32 + w];
        unsigned int w2 = hs[(size_t)s2 * 32 + w];
        unsigned int w3 = hs[(size_t)s3 * 32 + w];
        a2 += (unpack_bf2(w0) + unpack_bf2(w1)) + (unpack_bf2(w2) + unpack_bf2(w3));
    }
    for (; k < k1; k++) a2 += unpack_bf2(hs[(size_t)csr_src[k] * 32 + w]);
    float di = dinv[node];
    vf2 bp = *(const vf2*)(bias + 2 * w);
    float v0 = fmaxf(fmaf(a2.x, di, bp.x), 0.f);
    float v1 = fmaxf(fmaf(a2.y, di, bp.y), 0.f);
    h[(size_t)node * 32 + w] = pack2bf(v0, v1);
}

// ---- edge MLP: 8 lanes per edge-quad, direct per-lane index loads (round-6 form:
// shfl-distributed indices delayed gather issue), packed-f32 channel math ----
__global__ void __launch_bounds__(256) k_edge(const int* __restrict__ ei,
                       const unsigned int* __restrict__ P1, const unsigned int* __restrict__ P2,
                       const float* __restrict__ Wf, const int* __restrict__ flag,
                       void* __restrict__ out) {
    int tid = blockIdx.x * 256 + threadIdx.x;
    int g = tid >> 3;       // quad index: edges 4g .. 4g+3
    int k = tid & 7;        // sub-lane: channels j = 8k .. 8k+7
    int e0 = g * 4;
    if (e0 >= N_EDGES) return;  // N_EDGES % 4 == 0 -> e0..e0+3 all valid
    int f = flag[0];
    int r0 = load_row(ei, f, e0),     c0 = load_col(ei, f, e0);
    int r1 = load_row(ei, f, e0 + 1), c1 = load_col(ei, f, e0 + 1);
    int r2 = load_row(ei, f, e0 + 2), c2 = load_col(ei, f, e0 + 2);
    int r3 = load_row(ei, f, e0 + 3), c3 = load_col(ei, f, e0 + 3);
    // issue all 8 gathers before any compute
    uint4 ua0 = *(const uint4*)(P1 + (size_t)r0 * 32 + k * 4);
    uint4 ub0 = *(const uint4*)(P2 + (size_t)c0 * 32 + k * 4);
    uint4 ua1 = *(const uint4*)(P1 + (size_t)r1 * 32 + k * 4);
    uint4 ub1 = *(const uint4*)(P2 + (size_t)c1 * 32 + k * 4);
    uint4 ua2 = *(const uint4*)(P1 + (size_t)r2 * 32 + k * 4);
    uint4 ub2 = *(const uint4*)(P2 + (size_t)c2 * 32 + k * 4);
    uint4 ua3 = *(const uint4*)(P1 + (size_t)r3 * 32 + k * 4);
    uint4 ub3 = *(const uint4*)(P2 + (size_t)c3 * 32 + k * 4);
    // bias pairs and L2-weight pairs for this lane's 8 channels
    vf2 b2[4], wp[8];
#pragma unroll
    for (int t = 0; t < 4; t++) b2[t] = *(const vf2*)(Wf + WF_L1B + k * 8 + 2 * t);
#pragma unroll
    for (int t = 0; t < 8; t++) wp[t] = *(const vf2*)(Wf + WF_L2W + k * 16 + 2 * t);
    vf2 acc[4] = {{0.f, 0.f}, {0.f, 0.f}, {0.f, 0.f}, {0.f, 0.f}};
    auto edge_mlp = [&](const uint4& ua, const uint4& ub, int i) {
        unsigned int wa[4] = {ua.x, ua.y, ua.z, ua.w};
        unsigned int wb[4] = {ub.x, ub.y, ub.z, ub.w};
#pragma unroll
        for (int t = 0; t < 4; t++) {
            vf2 z = unpack_bf2(wa[t]) + unpack_bf2(wb[t]) + b2[t];
            z = __builtin_elementwise_max(z, (vf2){0.f, 0.f});
            acc[i] += z.x * wp[2 * t];      // (s0,s1) += z_ch0 * (w00,w01)
            acc[i] += z.y * wp[2 * t + 1];  // (s0,s1) += z_ch1 * (w10,w11)
        }
    };
    edge_mlp(ua0, ub0, 0);
    edge_mlp(ua1, ub1, 1);
    edge_mlp(ua2, ub2, 2);
    edge_mlp(ua3, ub3, 3);
    float s0[4], s1[4];
#pragma unroll
    for (int i = 0; i < 4; i++) { s0[i] = acc[i].x; s1[i] = acc[i].y; }
#pragma unroll
    for (int off = 1; off < 8; off <<= 1) {
#pragma unroll
        for (int i = 0; i < 4; i++) {
            s0[i] += __shfl_xor(s0[i], off);
            s1[i] += __shfl_xor(s1[i], off);
        }
    }
    if (k == 0) {
        float b0f = Wf[WF_L2B + 0], b1f = Wf[WF_L2B + 1];
        float z0[4], z1[4];
#pragma unroll
        for (int i = 0; i < 4; i++) {
            float za = s0[i] + b0f, zb = s1[i] + b1f;
            float m = fmaxf(za, zb);
            float lse = m + __logf(__expf(za - m) + __expf(zb - m));
            z0[i] = za - lse; z1[i] = zb - lse;
        }
        if (flag[1]) {
            uint4 v;
            v.x = pack2bf(z0[0], z1[0]); v.y = pack2bf(z0[1], z1[1]);
            v.z = pack2bf(z0[2], z1[2]); v.w = pack2bf(z0[3], z1[3]);
            *(uint4*)((unsigned int*)out + e0) = v;
        } else {
            float4 v01, v23;
            v01.x = z0[0]; v01.y = z1[0]; v01.z = z0[1]; v01.w = z1[1];
            v23.x = z0[2]; v23.y = z1[2]; v23.z = z0[3]; v23.w = z1[3];
            float4* op = (float4*)((float2*)out + e0);
            op[0] = v01;
            op[1] = v23;
        }
    }
}

extern "C" void kernel_launch(void* const* d_in, const int* in_sizes, int n_in,
                              void* d_out, int out_size, void* d_ws, size_t ws_size,
                              hipStream_t stream) {
    const void* x   = d_in[0];
    const int*  ei  = (const int*)d_in[1];

    char* ws = (char*)d_ws;
    constexpr size_t KB = 1024;

    int*   gcount = (int*)(ws);                    // 782 ints
    int*   bbase  = (int*)(ws + 8 * KB);           // 783 ints
    int*   flag   = (int*)(ws + 12 * KB);          // 8 B
    float* Wf     = (float*)(ws + 16 * KB);        // 83.2 KB -> ends ~99 KB
    float* dinv   = (float*)(ws + 400 * KB);       // 400 KB
    int*   rowptr = (int*)(ws + 800 * KB);         // 400 KB + 4
    unsigned int* tmp = (unsigned int*)(ws + 1300 * KB);  // 6400 KB -> ends 7700
    int*   csrsrc = (int*)(ws + 7700 * KB);        // 6400 KB -> ends 14100
    int*   bhist  = (int*)(ws + 14100 * KB);       // 392*782*4 = 1.2 MB -> ends ~15300
    int*   bofs   = (int*)(ws + 15400 * KB);       // 1.2 MB -> ends ~16600
    unsigned int* hs = (unsigned int*)(ws + 20500 * KB);  // 12800 KB (later P1)
    unsigned int* h  = (unsigned int*)(ws + 33300 * KB);  // 12800 KB (later P2)

    // detect + bucket-counter zero fused
    k_detect<<<SCAN_NB, 1024, 0, stream>>>(ei, (const unsigned int*)x, flag, gcount);
    k_prep<<<(WF_TOT + 255) / 256, 256, 0, stream>>>(d_in[2], d_in[4], d_in[6], d_in[3],
                                                     d_in[5], d_in[7], d_in[8], d_in[9],
                                                     flag, Wf);

    // bucketed CSR build: count -> bucket scan -> per-(block,bucket) scan -> scatter -> sub-CSR
    k_bcount<<<NSCB, 256, 0, stream>>>(ei, flag, gcount, bhist);
    k_bscan<<<1, 1024, 0, stream>>>(gcount, bbase, rowptr);
    k_bscan2<<<NBUCK, 512, 0, stream>>>(bhist, bbase, bofs);
    k_bscatter<<<NSCB, 256, 0, stream>>>(ei, flag, bofs, tmp);
    k_bcsr<<<NBUCK, 256, 0, stream>>>(tmp, bbase, rowptr, dinv, csrsrc);

    // wave-split grids: 2 waves/node-group(64) for gemms, 4 task-waves/64-node block for pair
    const int G = (N_NODES + 63) / 64;          // 1563 node groups
    const int gemm_blocks = (G * 2 + 3) / 4;    // 782

    // layer 1
    k_gemm_in_ws<<<gemm_blocks, 256, 0, stream>>>(x, Wf + WF_W1, dinv, hs, flag);
    k_agg<<<(N_NODES / 2 + 3) / 4, 256, 0, stream>>>(hs, rowptr, csrsrc, dinv, Wf + WF_B1, h);

    // layer 2
    k_gemm64_ws<<<gemm_blocks, 256, 0, stream>>>(h, Wf + WF_W2, dinv, hs);
    k_agg<<<(N_NODES / 2 + 3) / 4, 256, 0, stream>>>(hs, rowptr, csrsrc, dinv, Wf + WF_B2, h);

    // edge MLP: P1 -> hs, P2 in place on h (barrier-protected); original-order edge pass
    k_pair_ws<<<G, 256, 0, stream>>>(h, Wf + WF_L1W, hs);
    // 8 lanes per edge-quad -> 2 threads/edge -> 3.2M threads
    k_edge<<<(N_EDGES * 2 + 255) / 256, 256, 0, stream>>>(ei, hs, h, Wf, flag, d_out);
}

// Round 9
// 370.686 us; speedup vs baseline: 1.0404x; 1.0404x over previous
//
#include <hip/hip_runtime.h>
#include <hip/hip_bf16.h>

#define N_NODES 100000
#define N_EDGES 1600000
#define F_IN 128
#define HID 64
#define SCAN_NB 98   // ceil(100000/1024) — grid for detect
#define NBUCK 782    // ceil(100000/128) column buckets
#define BSH 7        // 128 nodes per bucket
#define NSCB 392     // blocks for count/scatter passes

typedef __attribute__((ext_vector_type(8))) short short8;
typedef __attribute__((ext_vector_type(2))) float vf2;

__device__ __forceinline__ float bfbits2f(unsigned short u) {
    union { unsigned int i; float f; } v;
    v.i = ((unsigned int)u) << 16;
    return v.f;
}
__device__ __forceinline__ unsigned short f2bfbits(float f) {
    union { float f; unsigned int i; } v;
    v.f = f;
    unsigned int r = v.i + 0x7FFFu + ((v.i >> 16) & 1u);  // RNE
    return (unsigned short)(r >> 16);
}
__device__ __forceinline__ unsigned int pack2bf(float a, float b) {
    return ((unsigned int)f2bfbits(b) << 16) | (unsigned int)f2bfbits(a);
}
__device__ __forceinline__ float lo_bf(unsigned int w) { return bfbits2f((unsigned short)(w & 0xFFFF)); }
__device__ __forceinline__ float hi_bf(unsigned int w) { return bfbits2f((unsigned short)(w >> 16)); }
// unpack u32 (2 packed bf16) -> float2: {lo<<16, hi&mask} reinterpreted. 2 VALU ops for 2 channels.
__device__ __forceinline__ vf2 unpack_bf2(unsigned int w) {
    union { unsigned int i[2]; vf2 f; } u;
    u.i[0] = w << 16;
    u.i[1] = w & 0xFFFF0000u;
    return u.f;
}

// ---- detect flags AND zero bucket counters; block 0 does flag logic ----
__global__ void k_detect(const int* __restrict__ ei, const unsigned int* __restrict__ x32,
                         int* __restrict__ flag, int* __restrict__ gcount) {
    int gid = blockIdx.x * 1024 + threadIdx.x;
    if (gid < NBUCK) gcount[gid] = 0;
    if (blockIdx.x != 0) return;
    __shared__ int s_odd, s_cnt;
    if (threadIdx.x == 0) { s_odd = 0; s_cnt = 0; }
    __syncthreads();
    int t = threadIdx.x;  // 1024 threads
    if (ei[2 * t + 1] != 0) atomicOr(&s_odd, 1);
    if (t < 256) {
        unsigned int u = x32[t];
        unsigned int e = (u >> 7) & 0xFF;
        if (e >= 0x68 && e <= 0x97) atomicAdd(&s_cnt, 1);
    }
    __syncthreads();
    if (t == 0) {
        flag[0] = (s_odd == 0) ? 1 : 0;
        flag[1] = (s_cnt >= 160) ? 1 : 0;
    }
}

__device__ __forceinline__ int clampN(int v) {
    v = v < 0 ? 0 : v;
    return v > (N_NODES - 1) ? (N_NODES - 1) : v;
}
__device__ __forceinline__ int load_row(const int* __restrict__ ei, int f, int e) {
    return clampN(f ? ei[2 * e] : ei[e]);
}
__device__ __forceinline__ int load_col(const int* __restrict__ ei, int f, int e) {
    return clampN(f ? ei[2 * (N_EDGES + e)] : ei[N_EDGES + e]);
}

// ---- fp32 weight scratch layout (floats) ----
#define WF_W1   0
#define WF_W2   8192
#define WF_L1W  12288
#define WF_B1   20480
#define WF_B2   20544
#define WF_L1B  20608
#define WF_L2W  20672
#define WF_L2B  20800
#define WF_TOT  20802

__global__ void k_prep(const void* W1, const void* W2, const void* L1W,
                       const void* b1, const void* b2, const void* L1b,
                       const void* L2W, const void* L2b,
                       const int* __restrict__ flag, float* __restrict__ Wf) {
    int idx = blockIdx.x * blockDim.x + threadIdx.x;
    if (idx >= WF_TOT) return;
    int bf = flag[1];
    const void* src; int k;
    if      (idx < WF_W2)  { src = W1;  k = idx; }
    else if (idx < WF_L1W) { src = W2;  k = idx - WF_W2; }
    else if (idx < WF_B1)  { src = L1W; k = idx - WF_L1W; }
    else if (idx < WF_B2)  { src = b1;  k = idx - WF_B1; }
    else if (idx < WF_L1B) { src = b2;  k = idx - WF_B2; }
    else if (idx < WF_L2W) { src = L1b; k = idx - WF_L1B; }
    else if (idx < WF_L2B) { src = L2W; k = idx - WF_L2W; }
    else                   { src = L2b; k = idx - WF_L2B; }
    Wf[idx] = bf ? bfbits2f(((const unsigned short*)src)[k]) : ((const float*)src)[k];
}

// ===== bucketed CSR build (deterministic, no global cursor atomics) =====

// ---- pass 1: LDS histogram; emit per-block hist matrix + global bucket counts ----
__global__ void __launch_bounds__(256) k_bcount(const int* __restrict__ ei,
                                                const int* __restrict__ flag,
                                                int* __restrict__ gcount,
                                                int* __restrict__ bhist) {
    __shared__ int hist[NBUCK];
    for (int t = threadIdx.x; t < NBUCK; t += 256) hist[t] = 0;
    __syncthreads();
    int f = flag[0];
    const int EPB = (N_EDGES + NSCB - 1) / NSCB;
    int base = blockIdx.x * EPB;
    int end = base + EPB; if (end > N_EDGES) end = N_EDGES;
    for (int e = base + threadIdx.x; e < end; e += 256)
        atomicAdd(&hist[load_col(ei, f, e) >> BSH], 1);
    __syncthreads();
    for (int t = threadIdx.x; t < NBUCK; t += 256) {
        int hv = hist[t];
        bhist[(size_t)blockIdx.x * NBUCK + t] = hv;   // coalesced
        if (hv) atomicAdd(&gcount[t], hv);
    }
}

// ---- pass 2a: exclusive scan of 782 bucket totals -> bbase ----
__global__ void k_bscan(const int* __restrict__ gcount,
                        int* __restrict__ bbase, int* __restrict__ rowptr) {
    __shared__ int s[1024];
    int t = threadIdx.x;
    int v = (t < NBUCK) ? gcount[t] : 0;
    s[t] = v; __syncthreads();
    for (int off = 1; off < 1024; off <<= 1) {
        int add = (t >= off) ? s[t - off] : 0;
        __syncthreads();
        s[t] += add;
        __syncthreads();
    }
    if (t < NBUCK) bbase[t] = s[t] - v;
    if (t == 0) { bbase[NBUCK] = N_EDGES; rowptr[N_NODES] = N_EDGES; }
}

// ---- pass 2b: per-(block,bucket) exact bases: bofs[b][blk] = bbase[b] + prefix ----
__global__ void __launch_bounds__(512) k_bscan2(const int* __restrict__ bhist,
                                                const int* __restrict__ bbase,
                                                int* __restrict__ bofs) {
    __shared__ int s[512];
    int b = blockIdx.x;
    int t = threadIdx.x;
    int v = (t < NSCB) ? bhist[(size_t)t * NBUCK + b] : 0;
    s[t] = v; __syncthreads();
    for (int off = 1; off < 512; off <<= 1) {
        int add = (t >= off) ? s[t - off] : 0;
        __syncthreads();
        s[t] += add;
        __syncthreads();
    }
    if (t < NSCB) bofs[(size_t)b * NSCB + t] = bbase[b] + s[t] - v;  // coalesced
}

// ---- pass 3: single-read scatter; rank via LDS atomics only ----
__global__ void __launch_bounds__(256) k_bscatter(const int* __restrict__ ei,
                                                  const int* __restrict__ flag,
                                                  const int* __restrict__ bofs,
                                                  unsigned int* __restrict__ tmp) {
    __shared__ int lbase[NBUCK];
    __shared__ int rank[NBUCK];
    for (int t = threadIdx.x; t < NBUCK; t += 256) {
        lbase[t] = bofs[(size_t)t * NSCB + blockIdx.x];
        rank[t] = 0;
    }
    __syncthreads();
    int f = flag[0];
    const int EPB = (N_EDGES + NSCB - 1) / NSCB;
    int base = blockIdx.x * EPB;
    int end = base + EPB; if (end > N_EDGES) end = N_EDGES;
    for (int e = base + threadIdx.x; e < end; e += 256) {
        int r = load_row(ei, f, e), c = load_col(ei, f, e);
        int b = c >> BSH;
        int rk = atomicAdd(&rank[b], 1);
        tmp[lbase[b] + rk] = ((unsigned int)r << BSH) | (unsigned int)(c & 127);
    }
}

// ---- pass 4: per-bucket sub-CSR entirely in LDS (emits csr_src, rowptr, dinv) ----
__global__ void __launch_bounds__(256) k_bcsr(const unsigned int* __restrict__ tmp,
                                              const int* __restrict__ bbase,
                                              int* __restrict__ rowptr,
                                              float* __restrict__ dinv,
                                              int* __restrict__ csr_src) {
    __shared__ int nh[128];    // per-node counts (stable after count phase)
    __shared__ int nrp[128];   // inclusive prefix
    __shared__ int ncur[128];  // placement cursor
    int nb = blockIdx.x;
    int s0 = bbase[nb], s1 = bbase[nb + 1];
    int cnt = s1 - s0;
    int t = threadIdx.x;
    if (t < 128) { nh[t] = 0; ncur[t] = 0; }
    __syncthreads();
    for (int i = t; i < cnt; i += 256)
        atomicAdd(&nh[tmp[s0 + i] & 127], 1);
    __syncthreads();
    if (t < 128) nrp[t] = nh[t];
    __syncthreads();
    for (int off = 1; off < 128; off <<= 1) {
        int add = (t < 128 && t >= off) ? nrp[t - off] : 0;
        __syncthreads();
        if (t < 128) nrp[t] += add;
        __syncthreads();
    }
    int nodeBase = nb * 128;
    if (t < 128 && nodeBase + t < N_NODES) {
        rowptr[nodeBase + t] = s0 + nrp[t] - nh[t];  // exclusive prefix
        dinv[nodeBase + t] = rsqrtf((float)(nh[t] + 1));
    }
    __syncthreads();
    for (int i = t; i < cnt; i += 256) {
        unsigned int v = tmp[s0 + i];
        int cl = v & 127;
        int rk = atomicAdd(&ncur[cl], 1);
        csr_src[s0 + (nrp[cl] - nh[cl]) + rk] = (int)(v >> BSH);
    }
}

// ===== node tables: packed bf16 rows, 32 u32 (=64 ch) per node =====
__device__ __forceinline__ void fma8_32(const float* xv, const float* __restrict__ W,
                                        int k0, int coloff, float* acc) {
#pragma unroll
    for (int t = 0; t < 8; t++) {
        const float* wr = W + (k0 + t) * 64 + coloff;
#pragma unroll
        for (int j = 0; j < 32; j++) acc[j] = fmaf(xv[t], wr[j], acc[j]);
    }
}

// ---- layer-1 GEMM (wave-split): x [N,128] @ Wf[128,64] -> hs bf16; scale=dinv ----
__global__ void __launch_bounds__(256) k_gemm_in_ws(const void* __restrict__ x,
                                                    const float* __restrict__ Wf,
                                                    const float* __restrict__ dinv,
                                                    unsigned int* __restrict__ hs,
                                                    const int* __restrict__ flag) {
    int wv = __builtin_amdgcn_readfirstlane(threadIdx.x >> 6);  // 0..3, scalar
    int wid = blockIdx.x * 4 + wv;
    int group = wid >> 1;
    int half = wid & 1;          // scalar: col-half
    int lane = threadIdx.x & 63;
    int node = group * 64 + lane;
    if (node >= N_NODES) return;
    int bf = flag[1];
    int coloff = half * 32;
    float acc[32];
#pragma unroll
    for (int j = 0; j < 32; j++) acc[j] = 0.f;
    if (bf) {
        const unsigned short* xp = (const unsigned short*)x + (size_t)node * F_IN;
#pragma unroll 2
        for (int k0 = 0; k0 < F_IN; k0 += 8) {
            short8 raw = *(const short8*)(xp + k0);
            float xv[8];
#pragma unroll
            for (int t = 0; t < 8; t++) xv[t] = bfbits2f((unsigned short)raw[t]);
            fma8_32(xv, Wf, k0, coloff, acc);
        }
    } else {
        const float* xp = (const float*)x + (size_t)node * F_IN;
#pragma unroll 2
        for (int k0 = 0; k0 < F_IN; k0 += 8) {
            float4 a = *(const float4*)(xp + k0);
            float4 b = *(const float4*)(xp + k0 + 4);
            float xv[8] = {a.x, a.y, a.z, a.w, b.x, b.y, b.z, b.w};
            fma8_32(xv, Wf, k0, coloff, acc);
        }
    }
    float s = dinv[node];
    unsigned int* op = hs + (size_t)node * 32 + half * 16;
#pragma unroll
    for (int j = 0; j < 32; j += 2) op[j >> 1] = pack2bf(acc[j] * s, acc[j + 1] * s);
}

// ---- layer-2 GEMM (wave-split): in bf16 [N,64] @ W[64][64] -> out bf16; scale=dinv ----
__global__ void __launch_bounds__(256) k_gemm64_ws(const unsigned int* __restrict__ in,
                                                   const float* __restrict__ W,
                                                   const float* __restrict__ dinv,
                                                   unsigned int* __restrict__ out) {
    int wv = __builtin_amdgcn_readfirstlane(threadIdx.x >> 6);
    int wid = blockIdx.x * 4 + wv;
    int group = wid >> 1;
    int half = wid & 1;
    int lane = threadIdx.x & 63;
    int node = group * 64 + lane;
    if (node >= N_NODES) return;
    int coloff = half * 32;
    float acc[32];
#pragma unroll
    for (int j = 0; j < 32; j++) acc[j] = 0.f;
    const unsigned short* hp = (const unsigned short*)(in + (size_t)node * 32);
#pragma unroll 2
    for (int k0 = 0; k0 < 64; k0 += 8) {
        short8 raw = *(const short8*)(hp + k0);
        float xv[8];
#pragma unroll
        for (int t = 0; t < 8; t++) xv[t] = bfbits2f((unsigned short)raw[t]);
        fma8_32(xv, W, k0, coloff, acc);
    }
    float s = dinv[node];
    unsigned int* op = out + (size_t)node * 32 + half * 16;
#pragma unroll
    for (int j = 0; j < 32; j += 2) op[j >> 1] = pack2bf(acc[j] * s, acc[j + 1] * s);
}

// ---- edge-MLP projections (wave-split, 4 tasks): block = 64 nodes x 4 waves ----
__global__ void __launch_bounds__(256) k_pair_ws(unsigned int* __restrict__ h,
                                                 const float* __restrict__ W,  // L1W [128][64]
                                                 unsigned int* __restrict__ P1) {
    int task = __builtin_amdgcn_readfirstlane(threadIdx.x >> 6);  // 0..3, scalar
    int lane = threadIdx.x & 63;
    int node = blockIdx.x * 64 + lane;
    bool valid = node < N_NODES;
    int coloff = (task & 1) * 32;
    const float* Wb = W + (task >> 1) * 64 * 64;  // k-row base: P1 rows 0.., P2 rows 64..
    float acc[32];
#pragma unroll
    for (int j = 0; j < 32; j++) acc[j] = 0.f;
    if (valid) {
        const unsigned short* hp = (const unsigned short*)(h + (size_t)node * 32);
#pragma unroll 2
        for (int k0 = 0; k0 < 64; k0 += 8) {
            short8 raw = *(const short8*)(hp + k0);
            float xv[8];
#pragma unroll
            for (int t = 0; t < 8; t++) xv[t] = bfbits2f((unsigned short)raw[t]);
            fma8_32(xv, Wb, k0, coloff, acc);
        }
    }
    __syncthreads();  // all reads of this block's 64 h-rows complete before P2 writes
    if (valid) {
        unsigned int* op = (task < 2 ? P1 : h) + (size_t)node * 32 + coloff / 2;
#pragma unroll
        for (int j = 0; j < 32; j += 2) op[j >> 1] = pack2bf(acc[j], acc[j + 1]);
    }
}

// ---- fused aggregate: wave = 2 nodes; 32 lanes/node; x8 unroll for gather ILP
// (measured optimum — x16 regressed: mean degree 16 means half the rows never
// enter a 16-wide main loop, and the 32-reg batch raised pressure) ----
__global__ void __launch_bounds__(256) k_agg(const unsigned int* __restrict__ hs,
                                             const int* __restrict__ rowptr,
                                             const int* __restrict__ csr_src,
                                             const float* __restrict__ dinv,
                                             const float* __restrict__ bias,
                                             unsigned int* __restrict__ h) {
    int waves_per_blk = blockDim.x >> 6;
    int wid = blockIdx.x * waves_per_blk + (threadIdx.x >> 6);
    int lane = threadIdx.x & 63;
    int half = lane >> 5;
    int w = lane & 31;
    int node = wid * 2 + half;
    if (node >= N_NODES) return;
    unsigned int sw = hs[(size_t)node * 32 + w];
    float a0 = lo_bf(sw), a1 = hi_bf(sw);
    int k = rowptr[node], k1 = rowptr[node + 1];
    for (; k + 7 < k1; k += 8) {
        int s0 = csr_src[k],     s1 = csr_src[k + 1], s2 = csr_src[k + 2], s3 = csr_src[k + 3];
        int s4 = csr_src[k + 4], s5 = csr_src[k + 5], s6 = csr_src[k + 6], s7 = csr_src[k + 7];
        unsigned int w0 = hs[(size_t)s0 * 32 + w];
        unsigned int w1 = hs[(size_t)s1 * 32 + w];
        unsigned int w2 = hs[(size_t)s2 * 32 + w];
        unsigned int w3 = hs[(size_t)s3 * 32 + w];
        unsigned int w4 = hs[(size_t)s4 * 32 + w];
        unsigned int w5 = hs[(size_t)s5 * 32 + w];
        unsigned int w6 = hs[(size_t)s6 * 32 + w];
        unsigned int w7 = hs[(size_t)s7 * 32 + w];
        a0 += ((lo_bf(w0) + lo_bf(w1)) + (lo_bf(w2) + lo_bf(w3)))
            + ((lo_bf(w4) + lo_bf(w5)) + (lo_bf(w6) + lo_bf(w7)));
        a1 += ((hi_bf(w0) + hi_bf(w1)) + (hi_bf(w2) + hi_bf(w3)))
            + ((hi_bf(w4) + hi_bf(w5)) + (hi_bf(w6) + hi_bf(w7)));
    }
    for (; k + 3 < k1; k += 4) {
        int s0 = csr_src[k], s1 = csr_src[k + 1], s2 = csr_src[k + 2], s3 = csr_src[k + 3];
        unsigned int w0 = hs[(size_t)s0 * 32 + w];
        unsigned int w1 = hs[(size_t)s1 * 32 + w];
        unsigned int w2 = hs[(size_t)s2 * 32 + w];
        unsigned int w3 = hs[(size_t)s3 * 32 + w];
        a0 += (lo_bf(w0) + lo_bf(w1)) + (lo_bf(w2) + lo_bf(w3));
        a1 += (hi_bf(w0) + hi_bf(w1)) + (hi_bf(w2) + hi_bf(w3));
    }
    for (; k < k1; k++) {
        unsigned int w0 = hs[(size_t)csr_src[k] * 32 + w];
        a0 += lo_bf(w0);
        a1 += hi_bf(w0);
    }
    float di = dinv[node];
    float v0 = fmaxf(fmaf(a0, di, bias[2 * w]), 0.f);
    float v1 = fmaxf(fmaf(a1, di, bias[2 * w + 1]), 0.f);
    h[(size_t)node * 32 + w] = pack2bf(v0, v1);
}

// ---- edge MLP: 8 lanes per edge-quad, direct per-lane index loads, packed-f32
// channel math (measured: 55.2 -> 53.0 µs, VGPR 36, occupancy 61%) ----
__global__ void __launch_bounds__(256) k_edge(const int* __restrict__ ei,
                       const unsigned int* __restrict__ P1, const unsigned int* __restrict__ P2,
                       const float* __restrict__ Wf, const int* __restrict__ flag,
                       void* __restrict__ out) {
    int tid = blockIdx.x * 256 + threadIdx.x;
    int g = tid >> 3;       // quad index: edges 4g .. 4g+3
    int k = tid & 7;        // sub-lane: channels j = 8k .. 8k+7
    int e0 = g * 4;
    if (e0 >= N_EDGES) return;  // N_EDGES % 4 == 0 -> e0..e0+3 all valid
    int f = flag[0];
    int r0 = load_row(ei, f, e0),     c0 = load_col(ei, f, e0);
    int r1 = load_row(ei, f, e0 + 1), c1 = load_col(ei, f, e0 + 1);
    int r2 = load_row(ei, f, e0 + 2), c2 = load_col(ei, f, e0 + 2);
    int r3 = load_row(ei, f, e0 + 3), c3 = load_col(ei, f, e0 + 3);
    // issue all 8 gathers before any compute
    uint4 ua0 = *(const uint4*)(P1 + (size_t)r0 * 32 + k * 4);
    uint4 ub0 = *(const uint4*)(P2 + (size_t)c0 * 32 + k * 4);
    uint4 ua1 = *(const uint4*)(P1 + (size_t)r1 * 32 + k * 4);
    uint4 ub1 = *(const uint4*)(P2 + (size_t)c1 * 32 + k * 4);
    uint4 ua2 = *(const uint4*)(P1 + (size_t)r2 * 32 + k * 4);
    uint4 ub2 = *(const uint4*)(P2 + (size_t)c2 * 32 + k * 4);
    uint4 ua3 = *(const uint4*)(P1 + (size_t)r3 * 32 + k * 4);
    uint4 ub3 = *(const uint4*)(P2 + (size_t)c3 * 32 + k * 4);
    // bias pairs and L2-weight pairs for this lane's 8 channels
    vf2 b2[4], wp[8];
#pragma unroll
    for (int t = 0; t < 4; t++) b2[t] = *(const vf2*)(Wf + WF_L1B + k * 8 + 2 * t);
#pragma unroll
    for (int t = 0; t < 8; t++) wp[t] = *(const vf2*)(Wf + WF_L2W + k * 16 + 2 * t);
    vf2 acc[4] = {{0.f, 0.f}, {0.f, 0.f}, {0.f, 0.f}, {0.f, 0.f}};
    auto edge_mlp = [&](const uint4& ua, const uint4& ub, int i) {
        unsigned int wa[4] = {ua.x, ua.y, ua.z, ua.w};
        unsigned int wb[4] = {ub.x, ub.y, ub.z, ub.w};
#pragma unroll
        for (int t = 0; t < 4; t++) {
            vf2 z = unpack_bf2(wa[t]) + unpack_bf2(wb[t]) + b2[t];
            z = __builtin_elementwise_max(z, (vf2){0.f, 0.f});
            acc[i] += z.x * wp[2 * t];      // (s0,s1) += z_ch0 * (w00,w01)
            acc[i] += z.y * wp[2 * t + 1];  // (s0,s1) += z_ch1 * (w10,w11)
        }
    };
    edge_mlp(ua0, ub0, 0);
    edge_mlp(ua1, ub1, 1);
    edge_mlp(ua2, ub2, 2);
    edge_mlp(ua3, ub3, 3);
    float s0[4], s1[4];
#pragma unroll
    for (int i = 0; i < 4; i++) { s0[i] = acc[i].x; s1[i] = acc[i].y; }
#pragma unroll
    for (int off = 1; off < 8; off <<= 1) {
#pragma unroll
        for (int i = 0; i < 4; i++) {
            s0[i] += __shfl_xor(s0[i], off);
            s1[i] += __shfl_xor(s1[i], off);
        }
    }
    if (k == 0) {
        float b0f = Wf[WF_L2B + 0], b1f = Wf[WF_L2B + 1];
        float z0[4], z1[4];
#pragma unroll
        for (int i = 0; i < 4; i++) {
            float za = s0[i] + b0f, zb = s1[i] + b1f;
            float m = fmaxf(za, zb);
            float lse = m + __logf(__expf(za - m) + __expf(zb - m));
            z0[i] = za - lse; z1[i] = zb - lse;
        }
        if (flag[1]) {
            uint4 v;
            v.x = pack2bf(z0[0], z1[0]); v.y = pack2bf(z0[1], z1[1]);
            v.z = pack2bf(z0[2], z1[2]); v.w = pack2bf(z0[3], z1[3]);
            *(uint4*)((unsigned int*)out + e0) = v;
        } else {
            float4 v01, v23;
            v01.x = z0[0]; v01.y = z1[0]; v01.z = z0[1]; v01.w = z1[1];
            v23.x = z0[2]; v23.y = z1[2]; v23.z = z0[3]; v23.w = z1[3];
            float4* op = (float4*)((float2*)out + e0);
            op[0] = v01;
            op[1] = v23;
        }
    }
}

extern "C" void kernel_launch(void* const* d_in, const int* in_sizes, int n_in,
                              void* d_out, int out_size, void* d_ws, size_t ws_size,
                              hipStream_t stream) {
    const void* x   = d_in[0];
    const int*  ei  = (const int*)d_in[1];

    char* ws = (char*)d_ws;
    constexpr size_t KB = 1024;

    int*   gcount = (int*)(ws);                    // 782 ints
    int*   bbase  = (int*)(ws + 8 * KB);           // 783 ints
    int*   flag   = (int*)(ws + 12 * KB);          // 8 B
    float* Wf     = (float*)(ws + 16 * KB);        // 83.2 KB -> ends ~99 KB
    float* dinv   = (float*)(ws + 400 * KB);       // 400 KB
    int*   rowptr = (int*)(ws + 800 * KB);         // 400 KB + 4
    unsigned int* tmp = (unsigned int*)(ws + 1300 * KB);  // 6400 KB -> ends 7700
    int*   csrsrc = (int*)(ws + 7700 * KB);        // 6400 KB -> ends 14100
    int*   bhist  = (int*)(ws + 14100 * KB);       // 392*782*4 = 1.2 MB -> ends ~15300
    int*   bofs   = (int*)(ws + 15400 * KB);       // 1.2 MB -> ends ~16600
    unsigned int* hs = (unsigned int*)(ws + 20500 * KB);  // 12800 KB (later P1)
    unsigned int* h  = (unsigned int*)(ws + 33300 * KB);  // 12800 KB (later P2)

    // detect + bucket-counter zero fused
    k_detect<<<SCAN_NB, 1024, 0, stream>>>(ei, (const unsigned int*)x, flag, gcount);
    k_prep<<<(WF_TOT + 255) / 256, 256, 0, stream>>>(d_in[2], d_in[4], d_in[6], d_in[3],
                                                     d_in[5], d_in[7], d_in[8], d_in[9],
                                                     flag, Wf);

    // bucketed CSR build: count -> bucket scan -> per-(block,bucket) scan -> scatter -> sub-CSR
    k_bcount<<<NSCB, 256, 0, stream>>>(ei, flag, gcount, bhist);
    k_bscan<<<1, 1024, 0, stream>>>(gcount, bbase, rowptr);
    k_bscan2<<<NBUCK, 512, 0, stream>>>(bhist, bbase, bofs);
    k_bscatter<<<NSCB, 256, 0, stream>>>(ei, flag, bofs, tmp);
    k_bcsr<<<NBUCK, 256, 0, stream>>>(tmp, bbase, rowptr, dinv, csrsrc);

    // wave-split grids: 2 waves/node-group(64) for gemms, 4 task-waves/64-node block for pair
    const int G = (N_NODES + 63) / 64;          // 1563 node groups
    const int gemm_blocks = (G * 2 + 3) / 4;    // 782

    // layer 1
    k_gemm_in_ws<<<gemm_blocks, 256, 0, stream>>>(x, Wf + WF_W1, dinv, hs, flag);
    k_agg<<<(N_NODES / 2 + 3) / 4, 256, 0, stream>>>(hs, rowptr, csrsrc, dinv, Wf + WF_B1, h);

    // layer 2
    k_gemm64_ws<<<gemm_blocks, 256, 0, stream>>>(h, Wf + WF_W2, dinv, hs);
    k_agg<<<(N_NODES / 2 + 3) / 4, 256, 0, stream>>>(hs, rowptr, csrsrc, dinv, Wf + WF_B2, h);

    // edge MLP: P1 -> hs, P2 in place on h (barrier-protected); original-order edge pass
    k_pair_ws<<<G, 256, 0, stream>>>(h, Wf + WF_L1W, hs);
    // 8 lanes per edge-quad -> 2 threads/edge -> 3.2M threads
    k_edge<<<(N_EDGES * 2 + 255) / 256, 256, 0, stream>>>(ei, hs, h, Wf, flag, d_out);
}

// Round 10
// 354.271 us; speedup vs baseline: 1.0886x; 1.0463x over previous
//
#include <hip/hip_runtime.h>
#include <hip/hip_bf16.h>

#define N_NODES 100000
#define N_EDGES 1600000
#define F_IN 128
#define HID 64
#define SCAN_NB 98   // ceil(100000/1024) — grid for detect
#define NBUCK 391    // ceil(100000/256) column buckets
#define BSH 8        // 256 nodes per bucket
#define NSCB 392     // blocks for count/scatter passes

typedef __attribute__((ext_vector_type(8))) short short8;
typedef __attribute__((ext_vector_type(2))) float vf2;

__device__ __forceinline__ float bfbits2f(unsigned short u) {
    union { unsigned int i; float f; } v;
    v.i = ((unsigned int)u) << 16;
    return v.f;
}
__device__ __forceinline__ unsigned short f2bfbits(float f) {
    union { float f; unsigned int i; } v;
    v.f = f;
    unsigned int r = v.i + 0x7FFFu + ((v.i >> 16) & 1u);  // RNE
    return (unsigned short)(r >> 16);
}
__device__ __forceinline__ unsigned int pack2bf(float a, float b) {
    return ((unsigned int)f2bfbits(b) << 16) | (unsigned int)f2bfbits(a);
}
__device__ __forceinline__ float lo_bf(unsigned int w) { return bfbits2f((unsigned short)(w & 0xFFFF)); }
__device__ __forceinline__ float hi_bf(unsigned int w) { return bfbits2f((unsigned short)(w >> 16)); }
// unpack u32 (2 packed bf16) -> float2: {lo<<16, hi&mask} reinterpreted. 2 VALU ops for 2 channels.
__device__ __forceinline__ vf2 unpack_bf2(unsigned int w) {
    union { unsigned int i[2]; vf2 f; } u;
    u.i[0] = w << 16;
    u.i[1] = w & 0xFFFF0000u;
    return u.f;
}

// ---- detect flags AND zero bucket counters; block 0 does flag logic ----
__global__ void k_detect(const int* __restrict__ ei, const unsigned int* __restrict__ x32,
                         int* __restrict__ flag, int* __restrict__ gcount) {
    int gid = blockIdx.x * 1024 + threadIdx.x;
    if (gid < NBUCK) gcount[gid] = 0;
    if (blockIdx.x != 0) return;
    __shared__ int s_odd, s_cnt;
    if (threadIdx.x == 0) { s_odd = 0; s_cnt = 0; }
    __syncthreads();
    int t = threadIdx.x;  // 1024 threads
    if (ei[2 * t + 1] != 0) atomicOr(&s_odd, 1);
    if (t < 256) {
        unsigned int u = x32[t];
        unsigned int e = (u >> 7) & 0xFF;
        if (e >= 0x68 && e <= 0x97) atomicAdd(&s_cnt, 1);
    }
    __syncthreads();
    if (t == 0) {
        flag[0] = (s_odd == 0) ? 1 : 0;
        flag[1] = (s_cnt >= 160) ? 1 : 0;
    }
}

__device__ __forceinline__ int clampN(int v) {
    v = v < 0 ? 0 : v;
    return v > (N_NODES - 1) ? (N_NODES - 1) : v;
}
__device__ __forceinline__ int load_row(const int* __restrict__ ei, int f, int e) {
    return clampN(f ? ei[2 * e] : ei[e]);
}
__device__ __forceinline__ int load_col(const int* __restrict__ ei, int f, int e) {
    return clampN(f ? ei[2 * (N_EDGES + e)] : ei[N_EDGES + e]);
}

// ---- fp32 weight scratch layout (floats) ----
#define WF_W1   0
#define WF_W2   8192
#define WF_L1W  12288
#define WF_B1   20480
#define WF_B2   20544
#define WF_L1B  20608
#define WF_L2W  20672
#define WF_L2B  20800
#define WF_TOT  20802

__global__ void k_prep(const void* W1, const void* W2, const void* L1W,
                       const void* b1, const void* b2, const void* L1b,
                       const void* L2W, const void* L2b,
                       const int* __restrict__ flag, float* __restrict__ Wf) {
    int idx = blockIdx.x * blockDim.x + threadIdx.x;
    if (idx >= WF_TOT) return;
    int bf = flag[1];
    const void* src; int k;
    if      (idx < WF_W2)  { src = W1;  k = idx; }
    else if (idx < WF_L1W) { src = W2;  k = idx - WF_W2; }
    else if (idx < WF_B1)  { src = L1W; k = idx - WF_L1W; }
    else if (idx < WF_B2)  { src = b1;  k = idx - WF_B1; }
    else if (idx < WF_L1B) { src = b2;  k = idx - WF_B2; }
    else if (idx < WF_L2W) { src = L1b; k = idx - WF_L1B; }
    else if (idx < WF_L2B) { src = L2W; k = idx - WF_L2W; }
    else                   { src = L2b; k = idx - WF_L2B; }
    Wf[idx] = bf ? bfbits2f(((const unsigned short*)src)[k]) : ((const float*)src)[k];
}

// ===== bucketed CSR build (deterministic, no global cursor atomics) =====

// ---- pass 1: LDS histogram; emit per-block hist matrix + global bucket counts ----
__global__ void __launch_bounds__(256) k_bcount(const int* __restrict__ ei,
                                                const int* __restrict__ flag,
                                                int* __restrict__ gcount,
                                                int* __restrict__ bhist) {
    __shared__ int hist[NBUCK];
    for (int t = threadIdx.x; t < NBUCK; t += 256) hist[t] = 0;
    __syncthreads();
    int f = flag[0];
    const int EPB = (N_EDGES + NSCB - 1) / NSCB;
    int base = blockIdx.x * EPB;
    int end = base + EPB; if (end > N_EDGES) end = N_EDGES;
    for (int e = base + threadIdx.x; e < end; e += 256)
        atomicAdd(&hist[load_col(ei, f, e) >> BSH], 1);
    __syncthreads();
    for (int t = threadIdx.x; t < NBUCK; t += 256) {
        int hv = hist[t];
        bhist[(size_t)blockIdx.x * NBUCK + t] = hv;   // coalesced
        if (hv) atomicAdd(&gcount[t], hv);
    }
}

// ---- pass 2a: exclusive scan of 391 bucket totals -> bbase ----
__global__ void k_bscan(const int* __restrict__ gcount,
                        int* __restrict__ bbase, int* __restrict__ rowptr) {
    __shared__ int s[512];
    int t = threadIdx.x;
    int v = (t < NBUCK) ? gcount[t] : 0;
    s[t] = v; __syncthreads();
    for (int off = 1; off < 512; off <<= 1) {
        int add = (t >= off) ? s[t - off] : 0;
        __syncthreads();
        s[t] += add;
        __syncthreads();
    }
    if (t < NBUCK) bbase[t] = s[t] - v;
    if (t == 0) { bbase[NBUCK] = N_EDGES; rowptr[N_NODES] = N_EDGES; }
}

// ---- pass 2b: per-(block,bucket) exact bases: bofs[b][blk] = bbase[b] + prefix ----
__global__ void __launch_bounds__(512) k_bscan2(const int* __restrict__ bhist,
                                                const int* __restrict__ bbase,
                                                int* __restrict__ bofs) {
    __shared__ int s[512];
    int b = blockIdx.x;
    int t = threadIdx.x;
    int v = (t < NSCB) ? bhist[(size_t)t * NBUCK + b] : 0;
    s[t] = v; __syncthreads();
    for (int off = 1; off < 512; off <<= 1) {
        int add = (t >= off) ? s[t - off] : 0;
        __syncthreads();
        s[t] += add;
        __syncthreads();
    }
    if (t < NSCB) bofs[(size_t)b * NSCB + t] = bbase[b] + s[t] - v;  // coalesced
}

// ---- pass 3: single-read scatter; rank via LDS atomics only ----
__global__ void __launch_bounds__(256) k_bscatter(const int* __restrict__ ei,
                                                  const int* __restrict__ flag,
                                                  const int* __restrict__ bofs,
                                                  unsigned int* __restrict__ tmp) {
    __shared__ int lbase[NBUCK];
    __shared__ int rank[NBUCK];
    for (int t = threadIdx.x; t < NBUCK; t += 256) {
        lbase[t] = bofs[(size_t)t * NSCB + blockIdx.x];
        rank[t] = 0;
    }
    __syncthreads();
    int f = flag[0];
    const int EPB = (N_EDGES + NSCB - 1) / NSCB;
    int base = blockIdx.x * EPB;
    int end = base + EPB; if (end > N_EDGES) end = N_EDGES;
    for (int e = base + threadIdx.x; e < end; e += 256) {
        int r = load_row(ei, f, e), c = load_col(ei, f, e);
        int b = c >> BSH;
        int rk = atomicAdd(&rank[b], 1);
        tmp[lbase[b] + rk] = ((unsigned int)r << BSH) | (unsigned int)(c & 255);
    }
}

// ---- pass 4: per-bucket sub-CSR entirely in LDS (emits csr_src, rowptr, dinv).
// 256 nodes/bucket, one node per thread. ----
__global__ void __launch_bounds__(256) k_bcsr(const unsigned int* __restrict__ tmp,
                                              const int* __restrict__ bbase,
                                              int* __restrict__ rowptr,
                                              float* __restrict__ dinv,
                                              int* __restrict__ csr_src) {
    __shared__ int nh[256];    // per-node counts (stable after count phase)
    __shared__ int nrp[256];   // inclusive prefix
    __shared__ int ncur[256];  // placement cursor
    int nb = blockIdx.x;
    int s0 = bbase[nb], s1 = bbase[nb + 1];
    int cnt = s1 - s0;
    int t = threadIdx.x;
    nh[t] = 0; ncur[t] = 0;
    __syncthreads();
    for (int i = t; i < cnt; i += 256)
        atomicAdd(&nh[tmp[s0 + i] & 255], 1);
    __syncthreads();
    nrp[t] = nh[t];
    __syncthreads();
    for (int off = 1; off < 256; off <<= 1) {
        int add = (t >= off) ? nrp[t - off] : 0;
        __syncthreads();
        nrp[t] += add;
        __syncthreads();
    }
    int nodeBase = nb * 256;
    if (nodeBase + t < N_NODES) {
        rowptr[nodeBase + t] = s0 + nrp[t] - nh[t];  // exclusive prefix
        dinv[nodeBase + t] = rsqrtf((float)(nh[t] + 1));
    }
    __syncthreads();
    for (int i = t; i < cnt; i += 256) {
        unsigned int v = tmp[s0 + i];
        int cl = v & 255;
        int rk = atomicAdd(&ncur[cl], 1);
        csr_src[s0 + (nrp[cl] - nh[cl]) + rk] = (int)(v >> BSH);
    }
}

// ===== node tables: packed bf16 rows, 32 u32 (=64 ch) per node =====
// packed-f32 inner loop: acc as vf2[16], weight rows as vf2 pairs, scalar x
// broadcast -> v_pk_fma_f32 halves VALU issue count (k_edge-verified trick)
__device__ __forceinline__ void fma8_32p(const float* xv, const float* __restrict__ W,
                                         int k0, int coloff, vf2* acc) {
#pragma unroll
    for (int t = 0; t < 8; t++) {
        const vf2* wr = (const vf2*)(W + (k0 + t) * 64 + coloff);
        vf2 xb = {xv[t], xv[t]};
#pragma unroll
        for (int j = 0; j < 16; j++) acc[j] += xb * wr[j];
    }
}

// ---- layer-1 GEMM (wave-split): x [N,128] @ Wf[128,64] -> hs bf16; scale=dinv ----
__global__ void __launch_bounds__(256) k_gemm_in_ws(const void* __restrict__ x,
                                                    const float* __restrict__ Wf,
                                                    const float* __restrict__ dinv,
                                                    unsigned int* __restrict__ hs,
                                                    const int* __restrict__ flag) {
    int wv = __builtin_amdgcn_readfirstlane(threadIdx.x >> 6);  // 0..3, scalar
    int wid = blockIdx.x * 4 + wv;
    int group = wid >> 1;
    int half = wid & 1;          // scalar: col-half
    int lane = threadIdx.x & 63;
    int node = group * 64 + lane;
    if (node >= N_NODES) return;
    int bf = flag[1];
    int coloff = half * 32;
    vf2 acc[16];
#pragma unroll
    for (int j = 0; j < 16; j++) acc[j] = (vf2){0.f, 0.f};
    if (bf) {
        const unsigned short* xp = (const unsigned short*)x + (size_t)node * F_IN;
#pragma unroll 2
        for (int k0 = 0; k0 < F_IN; k0 += 8) {
            short8 raw = *(const short8*)(xp + k0);
            float xv[8];
#pragma unroll
            for (int t = 0; t < 8; t++) xv[t] = bfbits2f((unsigned short)raw[t]);
            fma8_32p(xv, Wf, k0, coloff, acc);
        }
    } else {
        const float* xp = (const float*)x + (size_t)node * F_IN;
#pragma unroll 2
        for (int k0 = 0; k0 < F_IN; k0 += 8) {
            float4 a = *(const float4*)(xp + k0);
            float4 b = *(const float4*)(xp + k0 + 4);
            float xv[8] = {a.x, a.y, a.z, a.w, b.x, b.y, b.z, b.w};
            fma8_32p(xv, Wf, k0, coloff, acc);
        }
    }
    float s = dinv[node];
    unsigned int* op = hs + (size_t)node * 32 + half * 16;
#pragma unroll
    for (int j = 0; j < 16; j++) op[j] = pack2bf(acc[j].x * s, acc[j].y * s);
}

// ---- layer-2 GEMM (wave-split): in bf16 [N,64] @ W[64][64] -> out bf16; scale=dinv ----
__global__ void __launch_bounds__(256) k_gemm64_ws(const unsigned int* __restrict__ in,
                                                   const float* __restrict__ W,
                                                   const float* __restrict__ dinv,
                                                   unsigned int* __restrict__ out) {
    int wv = __builtin_amdgcn_readfirstlane(threadIdx.x >> 6);
    int wid = blockIdx.x * 4 + wv;
    int group = wid >> 1;
    int half = wid & 1;
    int lane = threadIdx.x & 63;
    int node = group * 64 + lane;
    if (node >= N_NODES) return;
    int coloff = half * 32;
    vf2 acc[16];
#pragma unroll
    for (int j = 0; j < 16; j++) acc[j] = (vf2){0.f, 0.f};
    const unsigned short* hp = (const unsigned short*)(in + (size_t)node * 32);
#pragma unroll 2
    for (int k0 = 0; k0 < 64; k0 += 8) {
        short8 raw = *(const short8*)(hp + k0);
        float xv[8];
#pragma unroll
        for (int t = 0; t < 8; t++) xv[t] = bfbits2f((unsigned short)raw[t]);
        fma8_32p(xv, W, k0, coloff, acc);
    }
    float s = dinv[node];
    unsigned int* op = out + (size_t)node * 32 + half * 16;
#pragma unroll
    for (int j = 0; j < 16; j++) op[j] = pack2bf(acc[j].x * s, acc[j].y * s);
}

// ---- edge-MLP projections (wave-split, 4 tasks): block = 64 nodes x 4 waves ----
__global__ void __launch_bounds__(256) k_pair_ws(unsigned int* __restrict__ h,
                                                 const float* __restrict__ W,  // L1W [128][64]
                                                 unsigned int* __restrict__ P1) {
    int task = __builtin_amdgcn_readfirstlane(threadIdx.x >> 6);  // 0..3, scalar
    int lane = threadIdx.x & 63;
    int node = blockIdx.x * 64 + lane;
    bool valid = node < N_NODES;
    int coloff = (task & 1) * 32;
    const float* Wb = W + (task >> 1) * 64 * 64;  // k-row base: P1 rows 0.., P2 rows 64..
    vf2 acc[16];
#pragma unroll
    for (int j = 0; j < 16; j++) acc[j] = (vf2){0.f, 0.f};
    if (valid) {
        const unsigned short* hp = (const unsigned short*)(h + (size_t)node * 32);
#pragma unroll 2
        for (int k0 = 0; k0 < 64; k0 += 8) {
            short8 raw = *(const short8*)(hp + k0);
            float xv[8];
#pragma unroll
            for (int t = 0; t < 8; t++) xv[t] = bfbits2f((unsigned short)raw[t]);
            fma8_32p(xv, Wb, k0, coloff, acc);
        }
    }
    __syncthreads();  // all reads of this block's 64 h-rows complete before P2 writes
    if (valid) {
        unsigned int* op = (task < 2 ? P1 : h) + (size_t)node * 32 + coloff / 2;
#pragma unroll
        for (int j = 0; j < 16; j++) op[j] = pack2bf(acc[j].x, acc[j].y);
    }
}

// ---- fused aggregate: wave = 2 nodes; 32 lanes/node; x8 unroll for gather ILP
// (measured optimum — x16 regressed) ----
__global__ void __launch_bounds__(256) k_agg(const unsigned int* __restrict__ hs,
                                             const int* __restrict__ rowptr,
                                             const int* __restrict__ csr_src,
                                             const float* __restrict__ dinv,
                                             const float* __restrict__ bias,
                                             unsigned int* __restrict__ h) {
    int waves_per_blk = blockDim.x >> 6;
    int wid = blockIdx.x * waves_per_blk + (threadIdx.x >> 6);
    int lane = threadIdx.x & 63;
    int half = lane >> 5;
    int w = lane & 31;
    int node = wid * 2 + half;
    if (node >= N_NODES) return;
    unsigned int sw = hs[(size_t)node * 32 + w];
    float a0 = lo_bf(sw), a1 = hi_bf(sw);
    int k = rowptr[node], k1 = rowptr[node + 1];
    for (; k + 7 < k1; k += 8) {
        int s0 = csr_src[k],     s1 = csr_src[k + 1], s2 = csr_src[k + 2], s3 = csr_src[k + 3];
        int s4 = csr_src[k + 4], s5 = csr_src[k + 5], s6 = csr_src[k + 6], s7 = csr_src[k + 7];
        unsigned int w0 = hs[(size_t)s0 * 32 + w];
        unsigned int w1 = hs[(size_t)s1 * 32 + w];
        unsigned int w2 = hs[(size_t)s2 * 32 + w];
        unsigned int w3 = hs[(size_t)s3 * 32 + w];
        unsigned int w4 = hs[(size_t)s4 * 32 + w];
        unsigned int w5 = hs[(size_t)s5 * 32 + w];
        unsigned int w6 = hs[(size_t)s6 * 32 + w];
        unsigned int w7 = hs[(size_t)s7 * 32 + w];
        a0 += ((lo_bf(w0) + lo_bf(w1)) + (lo_bf(w2) + lo_bf(w3)))
            + ((lo_bf(w4) + lo_bf(w5)) + (lo_bf(w6) + lo_bf(w7)));
        a1 += ((hi_bf(w0) + hi_bf(w1)) + (hi_bf(w2) + hi_bf(w3)))
            + ((hi_bf(w4) + hi_bf(w5)) + (hi_bf(w6) + hi_bf(w7)));
    }
    for (; k + 3 < k1; k += 4) {
        int s0 = csr_src[k], s1 = csr_src[k + 1], s2 = csr_src[k + 2], s3 = csr_src[k + 3];
        unsigned int w0 = hs[(size_t)s0 * 32 + w];
        unsigned int w1 = hs[(size_t)s1 * 32 + w];
        unsigned int w2 = hs[(size_t)s2 * 32 + w];
        unsigned int w3 = hs[(size_t)s3 * 32 + w];
        a0 += (lo_bf(w0) + lo_bf(w1)) + (lo_bf(w2) + lo_bf(w3));
        a1 += (hi_bf(w0) + hi_bf(w1)) + (hi_bf(w2) + hi_bf(w3));
    }
    for (; k < k1; k++) {
        unsigned int w0 = hs[(size_t)csr_src[k] * 32 + w];
        a0 += lo_bf(w0);
        a1 += hi_bf(w0);
    }
    float di = dinv[node];
    float v0 = fmaxf(fmaf(a0, di, bias[2 * w]), 0.f);
    float v1 = fmaxf(fmaf(a1, di, bias[2 * w + 1]), 0.f);
    h[(size_t)node * 32 + w] = pack2bf(v0, v1);
}

// ---- edge MLP: 8 lanes per edge-quad, direct per-lane index loads, packed-f32
// channel math (measured: 55.2 -> 53.0 µs, VGPR 36, occupancy 61%) ----
__global__ void __launch_bounds__(256) k_edge(const int* __restrict__ ei,
                       const unsigned int* __restrict__ P1, const unsigned int* __restrict__ P2,
                       const float* __restrict__ Wf, const int* __restrict__ flag,
                       void* __restrict__ out) {
    int tid = blockIdx.x * 256 + threadIdx.x;
    int g = tid >> 3;       // quad index: edges 4g .. 4g+3
    int k = tid & 7;        // sub-lane: channels j = 8k .. 8k+7
    int e0 = g * 4;
    if (e0 >= N_EDGES) return;  // N_EDGES % 4 == 0 -> e0..e0+3 all valid
    int f = flag[0];
    int r0 = load_row(ei, f, e0),     c0 = load_col(ei, f, e0);
    int r1 = load_row(ei, f, e0 + 1), c1 = load_col(ei, f, e0 + 1);
    int r2 = load_row(ei, f, e0 + 2), c2 = load_col(ei, f, e0 + 2);
    int r3 = load_row(ei, f, e0 + 3), c3 = load_col(ei, f, e0 + 3);
    // issue all 8 gathers before any compute
    uint4 ua0 = *(const uint4*)(P1 + (size_t)r0 * 32 + k * 4);
    uint4 ub0 = *(const uint4*)(P2 + (size_t)c0 * 32 + k * 4);
    uint4 ua1 = *(const uint4*)(P1 + (size_t)r1 * 32 + k * 4);
    uint4 ub1 = *(const uint4*)(P2 + (size_t)c1 * 32 + k * 4);
    uint4 ua2 = *(const uint4*)(P1 + (size_t)r2 * 32 + k * 4);
    uint4 ub2 = *(const uint4*)(P2 + (size_t)c2 * 32 + k * 4);
    uint4 ua3 = *(const uint4*)(P1 + (size_t)r3 * 32 + k * 4);
    uint4 ub3 = *(const uint4*)(P2 + (size_t)c3 * 32 + k * 4);
    // bias pairs and L2-weight pairs for this lane's 8 channels
    vf2 b2[4], wp[8];
#pragma unroll
    for (int t = 0; t < 4; t++) b2[t] = *(const vf2*)(Wf + WF_L1B + k * 8 + 2 * t);
#pragma unroll
    for (int t = 0; t < 8; t++) wp[t] = *(const vf2*)(Wf + WF_L2W + k * 16 + 2 * t);
    vf2 acc[4] = {{0.f, 0.f}, {0.f, 0.f}, {0.f, 0.f}, {0.f, 0.f}};
    auto edge_mlp = [&](const uint4& ua, const uint4& ub, int i) {
        unsigned int wa[4] = {ua.x, ua.y, ua.z, ua.w};
        unsigned int wb[4] = {ub.x, ub.y, ub.z, ub.w};
#pragma unroll
        for (int t = 0; t < 4; t++) {
            vf2 z = unpack_bf2(wa[t]) + unpack_bf2(wb[t]) + b2[t];
            z = __builtin_elementwise_max(z, (vf2){0.f, 0.f});
            acc[i] += z.x * wp[2 * t];      // (s0,s1) += z_ch0 * (w00,w01)
            acc[i] += z.y * wp[2 * t + 1];  // (s0,s1) += z_ch1 * (w10,w11)
        }
    };
    edge_mlp(ua0, ub0, 0);
    edge_mlp(ua1, ub1, 1);
    edge_mlp(ua2, ub2, 2);
    edge_mlp(ua3, ub3, 3);
    float s0[4], s1[4];
#pragma unroll
    for (int i = 0; i < 4; i++) { s0[i] = acc[i].x; s1[i] = acc[i].y; }
#pragma unroll
    for (int off = 1; off < 8; off <<= 1) {
#pragma unroll
        for (int i = 0; i < 4; i++) {
            s0[i] += __shfl_xor(s0[i], off);
            s1[i] += __shfl_xor(s1[i], off);
        }
    }
    if (k == 0) {
        float b0f = Wf[WF_L2B + 0], b1f = Wf[WF_L2B + 1];
        float z0[4], z1[4];
#pragma unroll
        for (int i = 0; i < 4; i++) {
            float za = s0[i] + b0f, zb = s1[i] + b1f;
            float m = fmaxf(za, zb);
            float lse = m + __logf(__expf(za - m) + __expf(zb - m));
            z0[i] = za - lse; z1[i] = zb - lse;
        }
        if (flag[1]) {
            uint4 v;
            v.x = pack2bf(z0[0], z1[0]); v.y = pack2bf(z0[1], z1[1]);
            v.z = pack2bf(z0[2], z1[2]); v.w = pack2bf(z0[3], z1[3]);
            *(uint4*)((unsigned int*)out + e0) = v;
        } else {
            float4 v01, v23;
            v01.x = z0[0]; v01.y = z1[0]; v01.z = z0[1]; v01.w = z1[1];
            v23.x = z0[2]; v23.y = z1[2]; v23.z = z0[3]; v23.w = z1[3];
            float4* op = (float4*)((float2*)out + e0);
            op[0] = v01;
            op[1] = v23;
        }
    }
}

extern "C" void kernel_launch(void* const* d_in, const int* in_sizes, int n_in,
                              void* d_out, int out_size, void* d_ws, size_t ws_size,
                              hipStream_t stream) {
    const void* x   = d_in[0];
    const int*  ei  = (const int*)d_in[1];

    char* ws = (char*)d_ws;
    constexpr size_t KB = 1024;

    int*   gcount = (int*)(ws);                    // 391 ints
    int*   bbase  = (int*)(ws + 8 * KB);           // 392 ints
    int*   flag   = (int*)(ws + 12 * KB);          // 8 B
    float* Wf     = (float*)(ws + 16 * KB);        // 83.2 KB -> ends ~99 KB
    float* dinv   = (float*)(ws + 400 * KB);       // 400 KB
    int*   rowptr = (int*)(ws + 800 * KB);         // 400 KB + 4
    unsigned int* tmp = (unsigned int*)(ws + 1300 * KB);  // 6400 KB -> ends 7700
    int*   csrsrc = (int*)(ws + 7700 * KB);        // 6400 KB -> ends 14100
    int*   bhist  = (int*)(ws + 14100 * KB);       // 392*391*4 = 0.6 MB
    int*   bofs   = (int*)(ws + 15400 * KB);       // 0.6 MB
    unsigned int* hs = (unsigned int*)(ws + 20500 * KB);  // 12800 KB (later P1)
    unsigned int* h  = (unsigned int*)(ws + 33300 * KB);  // 12800 KB (later P2)

    // detect + bucket-counter zero fused
    k_detect<<<SCAN_NB, 1024, 0, stream>>>(ei, (const unsigned int*)x, flag, gcount);
    k_prep<<<(WF_TOT + 255) / 256, 256, 0, stream>>>(d_in[2], d_in[4], d_in[6], d_in[3],
                                                     d_in[5], d_in[7], d_in[8], d_in[9],
                                                     flag, Wf);

    // bucketed CSR build: count -> bucket scan -> per-(block,bucket) scan -> scatter -> sub-CSR
    k_bcount<<<NSCB, 256, 0, stream>>>(ei, flag, gcount, bhist);
    k_bscan<<<1, 512, 0, stream>>>(gcount, bbase, rowptr);
    k_bscan2<<<NBUCK, 512, 0, stream>>>(bhist, bbase, bofs);
    k_bscatter<<<NSCB, 256, 0, stream>>>(ei, flag, bofs, tmp);
    k_bcsr<<<NBUCK, 256, 0, stream>>>(tmp, bbase, rowptr, dinv, csrsrc);

    // wave-split grids: 2 waves/node-group(64) for gemms, 4 task-waves/64-node block for pair
    const int G = (N_NODES + 63) / 64;          // 1563 node groups
    const int gemm_blocks = (G * 2 + 3) / 4;    // 782

    // layer 1
    k_gemm_in_ws<<<gemm_blocks, 256, 0, stream>>>(x, Wf + WF_W1, dinv, hs, flag);
    k_agg<<<(N_NODES / 2 + 3) / 4, 256, 0, stream>>>(hs, rowptr, csrsrc, dinv, Wf + WF_B1, h);

    // layer 2
    k_gemm64_ws<<<gemm_blocks, 256, 0, stream>>>(h, Wf + WF_W2, dinv, hs);
    k_agg<<<(N_NODES / 2 + 3) / 4, 256, 0, stream>>>(hs, rowptr, csrsrc, dinv, Wf + WF_B2, h);

    // edge MLP: P1 -> hs, P2 in place on h (barrier-protected); original-order edge pass
    k_pair_ws<<<G, 256, 0, stream>>>(h, Wf + WF_L1W, hs);
    // 8 lanes per edge-quad -> 2 threads/edge -> 3.2M threads
    k_edge<<<(N_EDGES * 2 + 255) / 256, 256, 0, stream>>>(ei, hs, h, Wf, flag, d_out);
}

// Round 11
// 339.289 us; speedup vs baseline: 1.1366x; 1.0442x over previous
//
#include <hip/hip_runtime.h>
#include <hip/hip_bf16.h>

#define N_NODES 100000
#define N_EDGES 1600000
#define F_IN 128
#define HID 64
#define SCAN_NB 98   // ceil(100000/1024) — grid for detect
#define NBUCK 391    // ceil(100000/256) column buckets
#define BSH 8        // 256 nodes per bucket
#define NSCB 392     // blocks for count/scatter passes

typedef __attribute__((ext_vector_type(8))) short short8;
typedef __attribute__((ext_vector_type(2))) float vf2;

__device__ __forceinline__ float bfbits2f(unsigned short u) {
    union { unsigned int i; float f; } v;
    v.i = ((unsigned int)u) << 16;
    return v.f;
}
__device__ __forceinline__ unsigned short f2bfbits(float f) {
    union { float f; unsigned int i; } v;
    v.f = f;
    unsigned int r = v.i + 0x7FFFu + ((v.i >> 16) & 1u);  // RNE
    return (unsigned short)(r >> 16);
}
__device__ __forceinline__ unsigned int pack2bf(float a, float b) {
    return ((unsigned int)f2bfbits(b) << 16) | (unsigned int)f2bfbits(a);
}
__device__ __forceinline__ float lo_bf(unsigned int w) { return bfbits2f((unsigned short)(w & 0xFFFF)); }
__device__ __forceinline__ float hi_bf(unsigned int w) { return bfbits2f((unsigned short)(w >> 16)); }
// unpack u32 (2 packed bf16) -> float2: {lo<<16, hi&mask} reinterpreted. 2 VALU ops for 2 channels.
__device__ __forceinline__ vf2 unpack_bf2(unsigned int w) {
    union { unsigned int i[2]; vf2 f; } u;
    u.i[0] = w << 16;
    u.i[1] = w & 0xFFFF0000u;
    return u.f;
}

// ---- detect flags AND zero bucket counters; block 0 does flag logic ----
__global__ void k_detect(const int* __restrict__ ei, const unsigned int* __restrict__ x32,
                         int* __restrict__ flag, int* __restrict__ gcount) {
    int gid = blockIdx.x * 1024 + threadIdx.x;
    if (gid < NBUCK) gcount[gid] = 0;
    if (blockIdx.x != 0) return;
    __shared__ int s_odd, s_cnt;
    if (threadIdx.x == 0) { s_odd = 0; s_cnt = 0; }
    __syncthreads();
    int t = threadIdx.x;  // 1024 threads
    if (ei[2 * t + 1] != 0) atomicOr(&s_odd, 1);
    if (t < 256) {
        unsigned int u = x32[t];
        unsigned int e = (u >> 7) & 0xFF;
        if (e >= 0x68 && e <= 0x97) atomicAdd(&s_cnt, 1);
    }
    __syncthreads();
    if (t == 0) {
        flag[0] = (s_odd == 0) ? 1 : 0;
        flag[1] = (s_cnt >= 160) ? 1 : 0;
    }
}

__device__ __forceinline__ int clampN(int v) {
    v = v < 0 ? 0 : v;
    return v > (N_NODES - 1) ? (N_NODES - 1) : v;
}
__device__ __forceinline__ int load_row(const int* __restrict__ ei, int f, int e) {
    return clampN(f ? ei[2 * e] : ei[e]);
}
__device__ __forceinline__ int load_col(const int* __restrict__ ei, int f, int e) {
    return clampN(f ? ei[2 * (N_EDGES + e)] : ei[N_EDGES + e]);
}

// ---- fp32 weight scratch layout (floats) ----
#define WF_W1   0
#define WF_W2   8192
#define WF_L1W  12288
#define WF_B1   20480
#define WF_B2   20544
#define WF_L1B  20608
#define WF_L2W  20672
#define WF_L2B  20800
#define WF_TOT  20802

__global__ void k_prep(const void* W1, const void* W2, const void* L1W,
                       const void* b1, const void* b2, const void* L1b,
                       const void* L2W, const void* L2b,
                       const int* __restrict__ flag, float* __restrict__ Wf) {
    int idx = blockIdx.x * blockDim.x + threadIdx.x;
    if (idx >= WF_TOT) return;
    int bf = flag[1];
    const void* src; int k;
    if      (idx < WF_W2)  { src = W1;  k = idx; }
    else if (idx < WF_L1W) { src = W2;  k = idx - WF_W2; }
    else if (idx < WF_B1)  { src = L1W; k = idx - WF_L1W; }
    else if (idx < WF_B2)  { src = b1;  k = idx - WF_B1; }
    else if (idx < WF_L1B) { src = b2;  k = idx - WF_B2; }
    else if (idx < WF_L2W) { src = L1b; k = idx - WF_L1B; }
    else if (idx < WF_L2B) { src = L2W; k = idx - WF_L2W; }
    else                   { src = L2b; k = idx - WF_L2B; }
    Wf[idx] = bf ? bfbits2f(((const unsigned short*)src)[k]) : ((const float*)src)[k];
}

// ===== bucketed CSR build (deterministic, no global cursor atomics) =====

// ---- pass 1: LDS histogram; emit per-block hist matrix + global bucket counts ----
__global__ void __launch_bounds__(256) k_bcount(const int* __restrict__ ei,
                                                const int* __restrict__ flag,
                                                int* __restrict__ gcount,
                                                int* __restrict__ bhist) {
    __shared__ int hist[NBUCK];
    for (int t = threadIdx.x; t < NBUCK; t += 256) hist[t] = 0;
    __syncthreads();
    int f = flag[0];
    const int EPB = (N_EDGES + NSCB - 1) / NSCB;
    int base = blockIdx.x * EPB;
    int end = base + EPB; if (end > N_EDGES) end = N_EDGES;
    for (int e = base + threadIdx.x; e < end; e += 256)
        atomicAdd(&hist[load_col(ei, f, e) >> BSH], 1);
    __syncthreads();
    for (int t = threadIdx.x; t < NBUCK; t += 256) {
        int hv = hist[t];
        bhist[(size_t)blockIdx.x * NBUCK + t] = hv;   // coalesced
        if (hv) atomicAdd(&gcount[t], hv);
    }
}

// ---- pass 2 (fused): block b scans the 391 bucket totals itself (writes bbase[b]),
// then scans its bucket's per-block column -> bofs[b][blk]. One launch instead of two. ----
__global__ void __launch_bounds__(512) k_bscan2(const int* __restrict__ gcount,
                                                const int* __restrict__ bhist,
                                                int* __restrict__ bbase,
                                                int* __restrict__ bofs,
                                                int* __restrict__ rowptr) {
    __shared__ int s[512];
    __shared__ int bb;
    int b = blockIdx.x;
    int t = threadIdx.x;
    // scan bucket totals -> this bucket's global base
    int v = (t < NBUCK) ? gcount[t] : 0;
    s[t] = v; __syncthreads();
    for (int off = 1; off < 512; off <<= 1) {
        int add = (t >= off) ? s[t - off] : 0;
        __syncthreads();
        s[t] += add;
        __syncthreads();
    }
    if (t == b) { bb = s[t] - v; bbase[b] = bb; }
    if (b == 0 && t == 0) { bbase[NBUCK] = N_EDGES; rowptr[N_NODES] = N_EDGES; }
    __syncthreads();
    int base_b = bb;
    // per-(block,bucket) exact bases for bucket b
    int v2 = (t < NSCB) ? bhist[(size_t)t * NBUCK + b] : 0;
    s[t] = v2; __syncthreads();
    for (int off = 1; off < 512; off <<= 1) {
        int add = (t >= off) ? s[t - off] : 0;
        __syncthreads();
        s[t] += add;
        __syncthreads();
    }
    if (t < NSCB) bofs[(size_t)b * NSCB + t] = base_b + s[t] - v2;  // coalesced
}

// ---- pass 3: LDS bucket-sort, then MONOTONE global writes (lbase[b] ascending in b
// -> the sorted sweep's addresses strictly increase; ~10x fewer write transactions
// than per-edge random bucket-run stores) ----
__global__ void __launch_bounds__(512) k_bscatter(const int* __restrict__ ei,
                                                  const int* __restrict__ flag,
                                                  const int* __restrict__ bofs,
                                                  unsigned int* __restrict__ tmp) {
    __shared__ unsigned int sortedv[4096];  // EPB=4082 padded
    __shared__ int sorteda[4096];
    __shared__ int lbase[NBUCK];
    __shared__ int hist[NBUCK];
    __shared__ int lofs[NBUCK];
    __shared__ int s[512];
    int t = threadIdx.x;
    for (int i = t; i < NBUCK; i += 512) {
        lbase[i] = bofs[(size_t)i * NSCB + blockIdx.x];
        hist[i] = 0;
    }
    __syncthreads();
    int f = flag[0];
    const int EPB = (N_EDGES + NSCB - 1) / NSCB;
    int base = blockIdx.x * EPB;
    int end = base + EPB; if (end > N_EDGES) end = N_EDGES;
    for (int e = base + t; e < end; e += 512)
        atomicAdd(&hist[load_col(ei, f, e) >> BSH], 1);
    __syncthreads();
    int v = (t < NBUCK) ? hist[t] : 0;
    s[t] = v; __syncthreads();
    for (int off = 1; off < 512; off <<= 1) {
        int add = (t >= off) ? s[t - off] : 0;
        __syncthreads();
        s[t] += add;
        __syncthreads();
    }
    if (t < NBUCK) { lofs[t] = s[t] - v; hist[t] = 0; }  // hist becomes rank cursor
    __syncthreads();
    for (int e = base + t; e < end; e += 512) {           // ei re-read is L2-warm
        int r = load_row(ei, f, e), c = load_col(ei, f, e);
        int b = c >> BSH;
        int rk = atomicAdd(&hist[b], 1);
        int sp = lofs[b] + rk;
        sortedv[sp] = ((unsigned int)r << BSH) | (unsigned int)(c & 255);
        sorteda[sp] = lbase[b] + rk;
    }
    __syncthreads();
    int cnt = end - base;
    for (int i = t; i < cnt; i += 512)
        tmp[sorteda[i]] = sortedv[i];
}

// ---- pass 4: per-bucket sub-CSR entirely in LDS (emits csr_src, rowptr, dinv).
// 256 nodes/bucket, one node per thread. ----
__global__ void __launch_bounds__(256) k_bcsr(const unsigned int* __restrict__ tmp,
                                              const int* __restrict__ bbase,
                                              int* __restrict__ rowptr,
                                              float* __restrict__ dinv,
                                              int* __restrict__ csr_src) {
    __shared__ int nh[256];    // per-node counts (stable after count phase)
    __shared__ int nrp[256];   // inclusive prefix
    __shared__ int ncur[256];  // placement cursor
    int nb = blockIdx.x;
    int s0 = bbase[nb], s1 = bbase[nb + 1];
    int cnt = s1 - s0;
    int t = threadIdx.x;
    nh[t] = 0; ncur[t] = 0;
    __syncthreads();
    for (int i = t; i < cnt; i += 256)
        atomicAdd(&nh[tmp[s0 + i] & 255], 1);
    __syncthreads();
    nrp[t] = nh[t];
    __syncthreads();
    for (int off = 1; off < 256; off <<= 1) {
        int add = (t >= off) ? nrp[t - off] : 0;
        __syncthreads();
        nrp[t] += add;
        __syncthreads();
    }
    int nodeBase = nb * 256;
    if (nodeBase + t < N_NODES) {
        rowptr[nodeBase + t] = s0 + nrp[t] - nh[t];  // exclusive prefix
        dinv[nodeBase + t] = rsqrtf((float)(nh[t] + 1));
    }
    __syncthreads();
    for (int i = t; i < cnt; i += 256) {
        unsigned int v = tmp[s0 + i];
        int cl = v & 255;
        int rk = atomicAdd(&ncur[cl], 1);
        csr_src[s0 + (nrp[cl] - nh[cl]) + rk] = (int)(v >> BSH);
    }
}

// ===== node tables: packed bf16 rows, 32 u32 (=64 ch) per node =====
// packed-f32 inner loop: acc as vf2[16], weight rows as vf2 pairs, scalar x
// broadcast -> v_pk_fma_f32 halves VALU issue count
__device__ __forceinline__ void fma8_32p(const float* xv, const float* __restrict__ W,
                                         int k0, int coloff, vf2* acc) {
#pragma unroll
    for (int t = 0; t < 8; t++) {
        const vf2* wr = (const vf2*)(W + (k0 + t) * 64 + coloff);
        vf2 xb = {xv[t], xv[t]};
#pragma unroll
        for (int j = 0; j < 16; j++) acc[j] += xb * wr[j];
    }
}

// ---- layer-1 GEMM (wave-split): x [N,128] @ Wf[128,64] -> hs bf16; scale=dinv ----
__global__ void __launch_bounds__(256) k_gemm_in_ws(const void* __restrict__ x,
                                                    const float* __restrict__ Wf,
                                                    const float* __restrict__ dinv,
                                                    unsigned int* __restrict__ hs,
                                                    const int* __restrict__ flag) {
    int wv = __builtin_amdgcn_readfirstlane(threadIdx.x >> 6);  // 0..3, scalar
    int wid = blockIdx.x * 4 + wv;
    int group = wid >> 1;
    int half = wid & 1;          // scalar: col-half
    int lane = threadIdx.x & 63;
    int node = group * 64 + lane;
    if (node >= N_NODES) return;
    int bf = flag[1];
    int coloff = half * 32;
    vf2 acc[16];
#pragma unroll
    for (int j = 0; j < 16; j++) acc[j] = (vf2){0.f, 0.f};
    if (bf) {
        const unsigned short* xp = (const unsigned short*)x + (size_t)node * F_IN;
#pragma unroll 2
        for (int k0 = 0; k0 < F_IN; k0 += 8) {
            short8 raw = *(const short8*)(xp + k0);
            float xv[8];
#pragma unroll
            for (int t = 0; t < 8; t++) xv[t] = bfbits2f((unsigned short)raw[t]);
            fma8_32p(xv, Wf, k0, coloff, acc);
        }
    } else {
        const float* xp = (const float*)x + (size_t)node * F_IN;
#pragma unroll 2
        for (int k0 = 0; k0 < F_IN; k0 += 8) {
            float4 a = *(const float4*)(xp + k0);
            float4 b = *(const float4*)(xp + k0 + 4);
            float xv[8] = {a.x, a.y, a.z, a.w, b.x, b.y, b.z, b.w};
            fma8_32p(xv, Wf, k0, coloff, acc);
        }
    }
    float s = dinv[node];
    unsigned int* op = hs + (size_t)node * 32 + half * 16;
#pragma unroll
    for (int j = 0; j < 16; j++) op[j] = pack2bf(acc[j].x * s, acc[j].y * s);
}

// ---- layer-2 GEMM (wave-split): in bf16 [N,64] @ W[64][64] -> out bf16; scale=dinv ----
__global__ void __launch_bounds__(256) k_gemm64_ws(const unsigned int* __restrict__ in,
                                                   const float* __restrict__ W,
                                                   const float* __restrict__ dinv,
                                                   unsigned int* __restrict__ out) {
    int wv = __builtin_amdgcn_readfirstlane(threadIdx.x >> 6);
    int wid = blockIdx.x * 4 + wv;
    int group = wid >> 1;
    int half = wid & 1;
    int lane = threadIdx.x & 63;
    int node = group * 64 + lane;
    if (node >= N_NODES) return;
    int coloff = half * 32;
    vf2 acc[16];
#pragma unroll
    for (int j = 0; j < 16; j++) acc[j] = (vf2){0.f, 0.f};
    const unsigned short* hp = (const unsigned short*)(in + (size_t)node * 32);
#pragma unroll 2
    for (int k0 = 0; k0 < 64; k0 += 8) {
        short8 raw = *(const short8*)(hp + k0);
        float xv[8];
#pragma unroll
        for (int t = 0; t < 8; t++) xv[t] = bfbits2f((unsigned short)raw[t]);
        fma8_32p(xv, W, k0, coloff, acc);
    }
    float s = dinv[node];
    unsigned int* op = out + (size_t)node * 32 + half * 16;
#pragma unroll
    for (int j = 0; j < 16; j++) op[j] = pack2bf(acc[j].x * s, acc[j].y * s);
}

// ---- edge-MLP projections (wave-split, 4 tasks): block = 64 nodes x 4 waves ----
__global__ void __launch_bounds__(256) k_pair_ws(unsigned int* __restrict__ h,
                                                 const float* __restrict__ W,  // L1W [128][64]
                                                 unsigned int* __restrict__ P1) {
    int task = __builtin_amdgcn_readfirstlane(threadIdx.x >> 6);  // 0..3, scalar
    int lane = threadIdx.x & 63;
    int node = blockIdx.x * 64 + lane;
    bool valid = node < N_NODES;
    int coloff = (task & 1) * 32;
    const float* Wb = W + (task >> 1) * 64 * 64;  // k-row base: P1 rows 0.., P2 rows 64..
    vf2 acc[16];
#pragma unroll
    for (int j = 0; j < 16; j++) acc[j] = (vf2){0.f, 0.f};
    if (valid) {
        const unsigned short* hp = (const unsigned short*)(h + (size_t)node * 32);
#pragma unroll 2
        for (int k0 = 0; k0 < 64; k0 += 8) {
            short8 raw = *(const short8*)(hp + k0);
            float xv[8];
#pragma unroll
            for (int t = 0; t < 8; t++) xv[t] = bfbits2f((unsigned short)raw[t]);
            fma8_32p(xv, Wb, k0, coloff, acc);
        }
    }
    __syncthreads();  // all reads of this block's 64 h-rows complete before P2 writes
    if (valid) {
        unsigned int* op = (task < 2 ? P1 : h) + (size_t)node * 32 + coloff / 2;
#pragma unroll
        for (int j = 0; j < 16; j++) op[j] = pack2bf(acc[j].x, acc[j].y);
    }
}

// ---- fused aggregate: wave = 4 nodes; 16 lanes/node; uint2 gathers.
// Each gather still covers one full 128-B hs row (16 lanes x 8 B); with the
// x8 unroll a wave holds 32 random lines in flight (2x the 2-node form). ----
__global__ void __launch_bounds__(256) k_agg(const unsigned int* __restrict__ hs,
                                             const int* __restrict__ rowptr,
                                             const int* __restrict__ csr_src,
                                             const float* __restrict__ dinv,
                                             const float* __restrict__ bias,
                                             unsigned int* __restrict__ h) {
    int wid = blockIdx.x * 4 + (threadIdx.x >> 6);
    int lane = threadIdx.x & 63;
    int q = lane >> 4;          // node within wave (0..3)
    int w = lane & 15;          // uint2 index within row: channels 4w..4w+3
    int node = wid * 4 + q;
    if (node >= N_NODES) return;
    const uint2* hp = (const uint2*)hs;  // row = 16 uint2
    uint2 sw = hp[(size_t)node * 16 + w];
    vf2 aA = unpack_bf2(sw.x), aB = unpack_bf2(sw.y);
    int k = rowptr[node], k1 = rowptr[node + 1];
    for (; k + 7 < k1; k += 8) {
        int s0 = csr_src[k],     s1 = csr_src[k + 1], s2 = csr_src[k + 2], s3 = csr_src[k + 3];
        int s4 = csr_src[k + 4], s5 = csr_src[k + 5], s6 = csr_src[k + 6], s7 = csr_src[k + 7];
        uint2 w0 = hp[(size_t)s0 * 16 + w];
        uint2 w1 = hp[(size_t)s1 * 16 + w];
        uint2 w2 = hp[(size_t)s2 * 16 + w];
        uint2 w3 = hp[(size_t)s3 * 16 + w];
        uint2 w4 = hp[(size_t)s4 * 16 + w];
        uint2 w5 = hp[(size_t)s5 * 16 + w];
        uint2 w6 = hp[(size_t)s6 * 16 + w];
        uint2 w7 = hp[(size_t)s7 * 16 + w];
        aA += ((unpack_bf2(w0.x) + unpack_bf2(w1.x)) + (unpack_bf2(w2.x) + unpack_bf2(w3.x)))
            + ((unpack_bf2(w4.x) + unpack_bf2(w5.x)) + (unpack_bf2(w6.x) + unpack_bf2(w7.x)));
        aB += ((unpack_bf2(w0.y) + unpack_bf2(w1.y)) + (unpack_bf2(w2.y) + unpack_bf2(w3.y)))
            + ((unpack_bf2(w4.y) + unpack_bf2(w5.y)) + (unpack_bf2(w6.y) + unpack_bf2(w7.y)));
    }
    for (; k + 3 < k1; k += 4) {
        int s0 = csr_src[k], s1 = csr_src[k + 1], s2 = csr_src[k + 2], s3 = csr_src[k + 3];
        uint2 w0 = hp[(size_t)s0 * 16 + w];
        uint2 w1 = hp[(size_t)s1 * 16 + w];
        uint2 w2 = hp[(size_t)s2 * 16 + w];
        uint2 w3 = hp[(size_t)s3 * 16 + w];
        aA += (unpack_bf2(w0.x) + unpack_bf2(w1.x)) + (unpack_bf2(w2.x) + unpack_bf2(w3.x));
        aB += (unpack_bf2(w0.y) + unpack_bf2(w1.y)) + (unpack_bf2(w2.y) + unpack_bf2(w3.y));
    }
    for (; k < k1; k++) {
        uint2 w0 = hp[(size_t)csr_src[k] * 16 + w];
        aA += unpack_bf2(w0.x);
        aB += unpack_bf2(w0.y);
    }
    float di = dinv[node];
    vf2 b0 = *(const vf2*)(bias + 4 * w);
    vf2 b1 = *(const vf2*)(bias + 4 * w + 2);
    float v0 = fmaxf(fmaf(aA.x, di, b0.x), 0.f);
    float v1 = fmaxf(fmaf(aA.y, di, b0.y), 0.f);
    float v2 = fmaxf(fmaf(aB.x, di, b1.x), 0.f);
    float v3 = fmaxf(fmaf(aB.y, di, b1.y), 0.f);
    uint2 ow; ow.x = pack2bf(v0, v1); ow.y = pack2bf(v2, v3);
    *(uint2*)(h + (size_t)node * 32 + 2 * w) = ow;
}

// ---- edge MLP: 8 lanes per edge-quad, direct per-lane index loads, packed-f32
// channel math (measured: 53.0 µs, VGPR 36, occupancy 61%) ----
__global__ void __launch_bounds__(256) k_edge(const int* __restrict__ ei,
                       const unsigned int* __restrict__ P1, const unsigned int* __restrict__ P2,
                       const float* __restrict__ Wf, const int* __restrict__ flag,
                       void* __restrict__ out) {
    int tid = blockIdx.x * 256 + threadIdx.x;
    int g = tid >> 3;       // quad index: edges 4g .. 4g+3
    int k = tid & 7;        // sub-lane: channels j = 8k .. 8k+7
    int e0 = g * 4;
    if (e0 >= N_EDGES) return;  // N_EDGES % 4 == 0 -> e0..e0+3 all valid
    int f = flag[0];
    int r0 = load_row(ei, f, e0),     c0 = load_col(ei, f, e0);
    int r1 = load_row(ei, f, e0 + 1), c1 = load_col(ei, f, e0 + 1);
    int r2 = load_row(ei, f, e0 + 2), c2 = load_col(ei, f, e0 + 2);
    int r3 = load_row(ei, f, e0 + 3), c3 = load_col(ei, f, e0 + 3);
    // issue all 8 gathers before any compute
    uint4 ua0 = *(const uint4*)(P1 + (size_t)r0 * 32 + k * 4);
    uint4 ub0 = *(const uint4*)(P2 + (size_t)c0 * 32 + k * 4);
    uint4 ua1 = *(const uint4*)(P1 + (size_t)r1 * 32 + k * 4);
    uint4 ub1 = *(const uint4*)(P2 + (size_t)c1 * 32 + k * 4);
    uint4 ua2 = *(const uint4*)(P1 + (size_t)r2 * 32 + k * 4);
    uint4 ub2 = *(const uint4*)(P2 + (size_t)c2 * 32 + k * 4);
    uint4 ua3 = *(const uint4*)(P1 + (size_t)r3 * 32 + k * 4);
    uint4 ub3 = *(const uint4*)(P2 + (size_t)c3 * 32 + k * 4);
    // bias pairs and L2-weight pairs for this lane's 8 channels
    vf2 b2[4], wp[8];
#pragma unroll
    for (int t = 0; t < 4; t++) b2[t] = *(const vf2*)(Wf + WF_L1B + k * 8 + 2 * t);
#pragma unroll
    for (int t = 0; t < 8; t++) wp[t] = *(const vf2*)(Wf + WF_L2W + k * 16 + 2 * t);
    vf2 acc[4] = {{0.f, 0.f}, {0.f, 0.f}, {0.f, 0.f}, {0.f, 0.f}};
    auto edge_mlp = [&](const uint4& ua, const uint4& ub, int i) {
        unsigned int wa[4] = {ua.x, ua.y, ua.z, ua.w};
        unsigned int wb[4] = {ub.x, ub.y, ub.z, ub.w};
#pragma unroll
        for (int t = 0; t < 4; t++) {
            vf2 z = unpack_bf2(wa[t]) + unpack_bf2(wb[t]) + b2[t];
            z = __builtin_elementwise_max(z, (vf2){0.f, 0.f});
            acc[i] += z.x * wp[2 * t];      // (s0,s1) += z_ch0 * (w00,w01)
            acc[i] += z.y * wp[2 * t + 1];  // (s0,s1) += z_ch1 * (w10,w11)
        }
    };
    edge_mlp(ua0, ub0, 0);
    edge_mlp(ua1, ub1, 1);
    edge_mlp(ua2, ub2, 2);
    edge_mlp(ua3, ub3, 3);
    float s0[4], s1[4];
#pragma unroll
    for (int i = 0; i < 4; i++) { s0[i] = acc[i].x; s1[i] = acc[i].y; }
#pragma unroll
    for (int off = 1; off < 8; off <<= 1) {
#pragma unroll
        for (int i = 0; i < 4; i++) {
            s0[i] += __shfl_xor(s0[i], off);
            s1[i] += __shfl_xor(s1[i], off);
        }
    }
    if (k == 0) {
        float b0f = Wf[WF_L2B + 0], b1f = Wf[WF_L2B + 1];
        float z0[4], z1[4];
#pragma unroll
        for (int i = 0; i < 4; i++) {
            float za = s0[i] + b0f, zb = s1[i] + b1f;
            float m = fmaxf(za, zb);
            float lse = m + __logf(__expf(za - m) + __expf(zb - m));
            z0[i] = za - lse; z1[i] = zb - lse;
        }
        if (flag[1]) {
            uint4 v;
            v.x = pack2bf(z0[0], z1[0]); v.y = pack2bf(z0[1], z1[1]);
            v.z = pack2bf(z0[2], z1[2]); v.w = pack2bf(z0[3], z1[3]);
            *(uint4*)((unsigned int*)out + e0) = v;
        } else {
            float4 v01, v23;
            v01.x = z0[0]; v01.y = z1[0]; v01.z = z0[1]; v01.w = z1[1];
            v23.x = z0[2]; v23.y = z1[2]; v23.z = z0[3]; v23.w = z1[3];
            float4* op = (float4*)((float2*)out + e0);
            op[0] = v01;
            op[1] = v23;
        }
    }
}

extern "C" void kernel_launch(void* const* d_in, const int* in_sizes, int n_in,
                              void* d_out, int out_size, void* d_ws, size_t ws_size,
                              hipStream_t stream) {
    const void* x   = d_in[0];
    const int*  ei  = (const int*)d_in[1];

    char* ws = (char*)d_ws;
    constexpr size_t KB = 1024;

    int*   gcount = (int*)(ws);                    // 391 ints
    int*   bbase  = (int*)(ws + 8 * KB);           // 392 ints
    int*   flag   = (int*)(ws + 12 * KB);          // 8 B
    float* Wf     = (float*)(ws + 16 * KB);        // 83.2 KB -> ends ~99 KB
    float* dinv   = (float*)(ws + 400 * KB);       // 400 KB
    int*   rowptr = (int*)(ws + 800 * KB);         // 400 KB + 4
    unsigned int* tmp = (unsigned int*)(ws + 1300 * KB);  // 6400 KB -> ends 7700
    int*   csrsrc = (int*)(ws + 7700 * KB);        // 6400 KB -> ends 14100
    int*   bhist  = (int*)(ws + 14100 * KB);       // 392*391*4 = 0.6 MB
    int*   bofs   = (int*)(ws + 15400 * KB);       // 0.6 MB
    unsigned int* hs = (unsigned int*)(ws + 20500 * KB);  // 12800 KB (later P1)
    unsigned int* h  = (unsigned int*)(ws + 33300 * KB);  // 12800 KB (later P2)

    // detect + bucket-counter zero fused
    k_detect<<<SCAN_NB, 1024, 0, stream>>>(ei, (const unsigned int*)x, flag, gcount);
    k_prep<<<(WF_TOT + 255) / 256, 256, 0, stream>>>(d_in[2], d_in[4], d_in[6], d_in[3],
                                                     d_in[5], d_in[7], d_in[8], d_in[9],
                                                     flag, Wf);

    // bucketed CSR build: count -> fused scans -> LDS-sorted scatter -> sub-CSR
    k_bcount<<<NSCB, 256, 0, stream>>>(ei, flag, gcount, bhist);
    k_bscan2<<<NBUCK, 512, 0, stream>>>(gcount, bhist, bbase, bofs, rowptr);
    k_bscatter<<<NSCB, 512, 0, stream>>>(ei, flag, bofs, tmp);
    k_bcsr<<<NBUCK, 256, 0, stream>>>(tmp, bbase, rowptr, dinv, csrsrc);

    // wave-split grids: 2 waves/node-group(64) for gemms, 4 task-waves/64-node block for pair
    const int G = (N_NODES + 63) / 64;          // 1563 node groups
    const int gemm_blocks = (G * 2 + 3) / 4;    // 782

    // layer 1
    k_gemm_in_ws<<<gemm_blocks, 256, 0, stream>>>(x, Wf + WF_W1, dinv, hs, flag);
    k_agg<<<(N_NODES + 15) / 16, 256, 0, stream>>>(hs, rowptr, csrsrc, dinv, Wf + WF_B1, h);

    // layer 2
    k_gemm64_ws<<<gemm_blocks, 256, 0, stream>>>(h, Wf + WF_W2, dinv, hs);
    k_agg<<<(N_NODES + 15) / 16, 256, 0, stream>>>(hs, rowptr, csrsrc, dinv, Wf + WF_B2, h);

    // edge MLP: P1 -> hs, P2 in place on h (barrier-protected); original-order edge pass
    k_pair_ws<<<G, 256, 0, stream>>>(h, Wf + WF_L1W, hs);
    // 8 lanes per edge-quad -> 2 threads/edge -> 3.2M threads
    k_edge<<<(N_EDGES * 2 + 255) / 256, 256, 0, stream>>>(ei, hs, h, Wf, flag, d_out);
}